// Round 6
// baseline (479.717 us; speedup 1.0000x reference)
//
#include <hip/hip_runtime.h>
#include <hip/hip_bf16.h>
#include <hip/hip_fp16.h>

constexpr int IN_DIM = 128;
constexpr int HID    = 256;

typedef short  bf16x8 __attribute__((ext_vector_type(8)));
typedef float  f32x4  __attribute__((ext_vector_type(4)));

__device__ inline ushort bf16_rn(float x) {
    uint u = __float_as_uint(x);
    uint r = u + 0x7FFFu + ((u >> 16) & 1u);
    return (ushort)(r >> 16);
}
__device__ inline void split_bf16(float x, ushort& hi, ushort& lo) {
    ushort h = bf16_rn(x);
    float hf = __uint_as_float(((uint)h) << 16);
    hi = h;
    lo = bf16_rn(x - hf);
}

// ---------------- setup kernels ----------------

__global__ void zero_int2(int* __restrict__ a, int* __restrict__ b, int n) {
    int i = blockIdx.x * blockDim.x + threadIdx.x;
    if (i < n) { a[i] = 0; b[i] = 0; }
}

__global__ void count_deg(const int* __restrict__ dst, int* __restrict__ deg, int e) {
    int i = blockIdx.x * blockDim.x + threadIdx.x;
    if (i < e) atomicAdd(&deg[dst[i]], 1);
}

// ---- device-wide exclusive scan of deg -> rowptr, 3 phases ----
// phase 1 also computes dinv (deg already final here)
__global__ __launch_bounds__(256) void scan_partial(const int* __restrict__ deg,
                                                    int* __restrict__ escan,
                                                    int* __restrict__ blocksum,
                                                    float* __restrict__ dinv, int n) {
    __shared__ int lds[256];
    int t = threadIdx.x;
    int i = blockIdx.x * 256 + t;
    int v = (i < n) ? deg[i] : 0;
    if (i < n) dinv[i] = rsqrtf((float)v + 1.0f);
    lds[t] = v;
    __syncthreads();
    for (int off = 1; off < 256; off <<= 1) {
        int a = lds[t];
        int w = (t >= off) ? lds[t - off] : 0;
        __syncthreads();
        lds[t] = a + w;
        __syncthreads();
    }
    if (i < n) escan[i] = lds[t] - v;
    if (t == 255) blocksum[blockIdx.x] = lds[255];
}

__global__ __launch_bounds__(256) void scan_blocksums(const int* __restrict__ blocksum,
                                                      int* __restrict__ blockoff,
                                                      int nb, int* __restrict__ rowptr_n) {
    __shared__ int lds[256];
    int t = threadIdx.x;
    int v = (t < nb) ? blocksum[t] : 0;
    lds[t] = v;
    __syncthreads();
    for (int off = 1; off < 256; off <<= 1) {
        int a = lds[t];
        int w = (t >= off) ? lds[t - off] : 0;
        __syncthreads();
        lds[t] = a + w;
        __syncthreads();
    }
    if (t < nb) blockoff[t] = lds[t] - v;
    if (t == 255) *rowptr_n = lds[255];
}

__global__ void scan_finalize(const int* __restrict__ escan, const int* __restrict__ blockoff,
                              int* __restrict__ rowptr, int n) {
    int i = blockIdx.x * 256 + threadIdx.x;
    if (i < n) rowptr[i] = escan[i] + blockoff[blockIdx.x];
}

__global__ void scatter_edges(const int* __restrict__ src, const int* __restrict__ dst,
                              const int* __restrict__ rowptr, int* __restrict__ cursor,
                              const float* __restrict__ dinv,
                              int* __restrict__ ssrc, float* __restrict__ ewt, int e) {
    int i = blockIdx.x * blockDim.x + threadIdx.x;
    if (i < e) {
        int d = dst[i];
        int s = src[i];
        int p = atomicAdd(&cursor[d], 1);
        int idx = rowptr[d] + p;
        ssrc[idx] = s;
        ewt[idx]  = dinv[s] * dinv[d];
    }
}

// x fp32 -> fp16
__global__ void convert_x_f16(const float* __restrict__ x, ushort* __restrict__ xh,
                              int total4) {
    int i = blockIdx.x * blockDim.x + threadIdx.x;
    if (i >= total4) return;
    float4 v = *(const float4*)(x + (size_t)i * 4);
    ushort4 o;
    o.x = __half_as_ushort(__float2half(v.x));
    o.y = __half_as_ushort(__float2half(v.y));
    o.z = __half_as_ushort(__float2half(v.z));
    o.w = __half_as_ushort(__float2half(v.w));
    *(ushort4*)(xh + (size_t)i * 4) = o;
}

// ---------------- weight preconvert: B[K][256] fp32 -> hi/lo bf16 panels ----
// layout: [k>>5][n][k&31] (ushort), panel stride 256*32
template <int K>
__global__ void convert_B(const float* __restrict__ B, ushort* __restrict__ Bh,
                          ushort* __restrict__ Bl) {
    int id = blockIdx.x * 256 + threadIdx.x;
    if (id >= K * 64) return;
    int k  = id >> 6;
    int n4 = (id & 63) * 4;
    float4 v = *(const float4*)(B + (size_t)k * 256 + n4);
    size_t base = (size_t)(k >> 5) * (256 * 32) + (k & 31);
    float vv[4] = {v.x, v.y, v.z, v.w};
#pragma unroll
    for (int c = 0; c < 4; c++) {
        ushort h, l;
        split_bf16(vv[c], h, l);
        Bh[base + (size_t)(n4 + c) * 32] = h;
        Bl[base + (size_t)(n4 + c) * 32] = l;
    }
}

// ---------------- fused aggregate + MFMA split-bf16 GEMM ----------------
// Per block: 64 dst nodes. Phase 1: wave w aggregates nodes [w*16, w*16+16)
// into registers (lane holds VH=K/64 feats/node, fp32 accum from fp16 rows).
// Phase 2: K-loop stages A per-chunk from (pre-split) registers, B from
// global panels; 16x16x32 bf16 MFMA, 3-product split-bf16.
// MODE 1: C16[M,256] = fp16(relu(agg@B + bias))
// MODE 2: out[M,2]  = relu(agg@B + bias) @ Wl + bl
template <int K, int MODE>
__global__ __launch_bounds__(256, 2) void fused_agg_gemm(
    const ushort* __restrict__ h,      // fp16 rows [n][K]
    const int* __restrict__ rowptr,
    const int* __restrict__ ssrc,
    const float* __restrict__ ewt,
    const float* __restrict__ dinv,
    const ushort* __restrict__ Bh, const ushort* __restrict__ Bl,
    const float* __restrict__ bias,
    ushort* __restrict__ C16,
    const float* __restrict__ Wl, const float* __restrict__ bl,
    float* __restrict__ out, int M) {

    constexpr int VH = K / 64;   // fp16 feats per lane: 2 or 4
    constexpr int PW = VH / 2;   // packed 32-bit words per node: 1 or 2

    __shared__ ushort Ah[64][40], Al[64][40];
    __shared__ ushort Bsh[256][40], Bsl[256][40];
    __shared__ float part[4][64][2];

    int tid  = threadIdx.x;
    int w    = tid >> 6;
    int lane = tid & 63;
    int l15  = lane & 15;
    int quad = lane >> 4;
    int row0 = blockIdx.x * 64;

    // ---- phase 1: aggregate 16 nodes per wave into registers ----
    float accg[16][VH];
#pragma unroll
    for (int i = 0; i < 16; i++) {
        int node = row0 + w * 16 + i;
#pragma unroll
        for (int v = 0; v < VH; v++) accg[i][v] = 0.f;
        if (node < M) {
            float di = dinv[node];
            float sw = di * di;
            const ushort* rp = h + (size_t)node * K + lane * VH;
            if constexpr (VH == 4) {
                uint2 u = *(const uint2*)rp;
                float2 fa = __half22float2(*(__half2*)&u.x);
                float2 fb = __half22float2(*(__half2*)&u.y);
                accg[i][0] = fa.x * sw; accg[i][1] = fa.y * sw;
                accg[i][2] = fb.x * sw; accg[i][3] = fb.y * sw;
            } else {
                uint u = *(const uint*)rp;
                float2 fa = __half22float2(*(__half2*)&u);
                accg[i][0] = fa.x * sw; accg[i][1] = fa.y * sw;
            }
            int beg = rowptr[node], fin = rowptr[node + 1];
#pragma unroll 2
            for (int j = beg; j < fin; j++) {
                int   s  = ssrc[j];
                float wg = ewt[j];
                const ushort* r = h + (size_t)s * K + lane * VH;
                if constexpr (VH == 4) {
                    uint2 u = *(const uint2*)r;
                    float2 fa = __half22float2(*(__half2*)&u.x);
                    float2 fb = __half22float2(*(__half2*)&u.y);
                    accg[i][0] += fa.x * wg; accg[i][1] += fa.y * wg;
                    accg[i][2] += fb.x * wg; accg[i][3] += fb.y * wg;
                } else {
                    uint u = *(const uint*)r;
                    float2 fa = __half22float2(*(__half2*)&u);
                    accg[i][0] += fa.x * wg; accg[i][1] += fa.y * wg;
                }
            }
        }
    }

    // pre-split to packed bf16 hi/lo (full-wave VALU, done once)
    uint hpk[16][PW], lpk[16][PW];
#pragma unroll
    for (int i = 0; i < 16; i++)
#pragma unroll
        for (int p = 0; p < PW; p++) {
            ushort h0, l0, h1, l1;
            split_bf16(accg[i][2 * p],     h0, l0);
            split_bf16(accg[i][2 * p + 1], h1, l1);
            hpk[i][p] = (uint)h0 | ((uint)h1 << 16);
            lpk[i][p] = (uint)l0 | ((uint)l1 << 16);
        }

    // ---- phase 2: K-loop GEMM ----
    f32x4 acc[4][4] = {};
    int fbase = lane * VH;  // first feature this lane owns

#pragma unroll
    for (int k0 = 0; k0 < K; k0 += 32) {
        // B chunk global loads first
        size_t panel = (size_t)(k0 >> 5) * (256 * 32) + (size_t)tid * 32;
        const uint4* bhsrc = (const uint4*)(Bh + panel);
        const uint4* blsrc = (const uint4*)(Bl + panel);
        uint4 bh0 = bhsrc[0], bh1 = bhsrc[1], bh2 = bhsrc[2], bh3 = bhsrc[3];
        uint4 bl0 = blsrc[0], bl1 = blsrc[1], bl2 = blsrc[2], bl3 = blsrc[3];

        __syncthreads();  // previous chunk's fragment reads done

        // A chunk from registers (lanes owning feats [k0, k0+32))
        if (fbase >= k0 && fbase < k0 + 32) {
            int col = fbase - k0;
#pragma unroll
            for (int i = 0; i < 16; i++) {
                int r = w * 16 + i;
                if constexpr (PW == 2) {
                    *(uint2*)&Ah[r][col] = make_uint2(hpk[i][0], hpk[i][1]);
                    *(uint2*)&Al[r][col] = make_uint2(lpk[i][0], lpk[i][1]);
                } else {
                    *(uint*)&Ah[r][col] = hpk[i][0];
                    *(uint*)&Al[r][col] = lpk[i][0];
                }
            }
        }
        {
            uint4* d0 = (uint4*)&Bsh[tid][0];
            d0[0]=bh0; d0[1]=bh1; d0[2]=bh2; d0[3]=bh3;
            uint4* d1 = (uint4*)&Bsl[tid][0];
            d1[0]=bl0; d1[1]=bl1; d1[2]=bl2; d1[3]=bl3;
        }
        __syncthreads();

        bf16x8 af_h[4], af_l[4], bf_h[4], bf_l[4];
#pragma unroll
        for (int i = 0; i < 4; i++) {
            af_h[i] = *(const bf16x8*)&Ah[i * 16 + l15][quad * 8];
            af_l[i] = *(const bf16x8*)&Al[i * 16 + l15][quad * 8];
        }
#pragma unroll
        for (int j = 0; j < 4; j++) {
            int nn = w * 64 + j * 16 + l15;
            bf_h[j] = *(const bf16x8*)&Bsh[nn][quad * 8];
            bf_l[j] = *(const bf16x8*)&Bsl[nn][quad * 8];
        }
#pragma unroll
        for (int i = 0; i < 4; i++)
#pragma unroll
            for (int j = 0; j < 4; j++) {
                acc[i][j] = __builtin_amdgcn_mfma_f32_16x16x32_bf16(af_h[i], bf_h[j], acc[i][j], 0, 0, 0);
                acc[i][j] = __builtin_amdgcn_mfma_f32_16x16x32_bf16(af_h[i], bf_l[j], acc[i][j], 0, 0, 0);
                acc[i][j] = __builtin_amdgcn_mfma_f32_16x16x32_bf16(af_l[i], bf_h[j], acc[i][j], 0, 0, 0);
            }
    }

    float bj[4];
#pragma unroll
    for (int j = 0; j < 4; j++) bj[j] = bias[w * 64 + j * 16 + l15];

    if constexpr (MODE == 1) {
#pragma unroll
        for (int i = 0; i < 4; i++)
#pragma unroll
            for (int reg = 0; reg < 4; reg++) {
                int r = row0 + i * 16 + quad * 4 + reg;
                if (r < M) {
                    ushort* cp = C16 + (size_t)r * 256 + w * 64 + l15;
#pragma unroll
                    for (int j = 0; j < 4; j++) {
                        float v = fmaxf(acc[i][j][reg] + bj[j], 0.f);
                        cp[j * 16] = __half_as_ushort(__float2half(v));
                    }
                }
            }
    } else {
        float wl0[4], wl1[4];
#pragma unroll
        for (int j = 0; j < 4; j++) {
            int cj = w * 64 + j * 16 + l15;
            float2 wv = *(const float2*)(Wl + cj * 2);
            wl0[j] = wv.x; wl1[j] = wv.y;
        }
#pragma unroll
        for (int i = 0; i < 4; i++)
#pragma unroll
            for (int reg = 0; reg < 4; reg++) {
                float s0 = 0.f, s1 = 0.f;
#pragma unroll
                for (int j = 0; j < 4; j++) {
                    float v = fmaxf(acc[i][j][reg] + bj[j], 0.f);
                    s0 += v * wl0[j];
                    s1 += v * wl1[j];
                }
#pragma unroll
                for (int off = 1; off < 16; off <<= 1) {
                    s0 += __shfl_xor(s0, off);
                    s1 += __shfl_xor(s1, off);
                }
                if (l15 == 0) {
                    int r = i * 16 + quad * 4 + reg;
                    part[w][r][0] = s0;
                    part[w][r][1] = s1;
                }
            }
        __syncthreads();
        if (tid < 128) {
            int r = tid >> 1, o = tid & 1;
            int grr = row0 + r;
            if (grr < M) {
                float s = part[0][r][o] + part[1][r][o] + part[2][r][o] + part[3][r][o] + bl[o];
                out[(size_t)grr * 2 + o] = s;
            }
        }
    }
}

// ---------------- launch ----------------

extern "C" void kernel_launch(void* const* d_in, const int* in_sizes, int n_in,
                              void* d_out, int out_size, void* d_ws, size_t ws_size,
                              hipStream_t stream) {
    const float* x  = (const float*)d_in[0];
    const int*   ei = (const int*)d_in[1];
    const float* W1 = (const float*)d_in[2];
    const float* b1 = (const float*)d_in[3];
    const float* W2 = (const float*)d_in[4];
    const float* b2 = (const float*)d_in[5];
    const float* Wl = (const float*)d_in[6];
    const float* bl = (const float*)d_in[7];
    float* out = (float*)d_out;

    int n = in_sizes[0] / IN_DIM;  // 50000
    int e = in_sizes[1] / 2;       // 600000
    const int* src = ei;
    const int* dst = ei + e;

    char* ws = (char*)d_ws;
    size_t off = 0;
    auto alloc = [&](size_t bytes) -> void* {
        void* p = ws + off;
        off += (bytes + 255) & ~(size_t)255;
        return p;
    };
    int*    deg    = (int*)alloc((size_t)n * 4);
    int*    cursor = (int*)alloc((size_t)n * 4);
    float*  dinv   = (float*)alloc((size_t)n * 4);
    int*    rowptr = (int*)alloc((size_t)(n + 1) * 4);
    int*    escan  = (int*)alloc((size_t)n * 4);
    int*    bsum   = (int*)alloc(256 * 4);
    int*    boff   = (int*)alloc(256 * 4);
    int*    ssrc   = (int*)alloc((size_t)e * 4);
    float*  ewt    = (float*)alloc((size_t)e * 4);
    ushort* xh     = (ushort*)alloc((size_t)n * IN_DIM * 2);
    ushort* h1     = (ushort*)alloc((size_t)n * HID * 2);
    ushort* B1h    = (ushort*)alloc((size_t)IN_DIM * 256 * 2);
    ushort* B1l    = (ushort*)alloc((size_t)IN_DIM * 256 * 2);
    ushort* B2h    = (ushort*)alloc((size_t)HID * 256 * 2);
    ushort* B2l    = (ushort*)alloc((size_t)HID * 256 * 2);

    int nb = (n + 255) / 256;   // 196 (<= 256 required by scan_blocksums)
    int eb = (e + 255) / 256;

    zero_int2<<<nb, 256, 0, stream>>>(deg, cursor, n);
    count_deg<<<eb, 256, 0, stream>>>(dst, deg, e);

    scan_partial<<<nb, 256, 0, stream>>>(deg, escan, bsum, dinv, n);
    scan_blocksums<<<1, 256, 0, stream>>>(bsum, boff, nb, rowptr + n);
    scan_finalize<<<nb, 256, 0, stream>>>(escan, boff, rowptr, n);

    scatter_edges<<<eb, 256, 0, stream>>>(src, dst, rowptr, cursor, dinv, ssrc, ewt, e);

    int total4 = n * IN_DIM / 4;
    convert_x_f16<<<(total4 + 255) / 256, 256, 0, stream>>>(x, xh, total4);
    convert_B<IN_DIM><<<IN_DIM * 64 / 256, 256, 0, stream>>>(W1, B1h, B1l);
    convert_B<HID><<<HID * 64 / 256, 256, 0, stream>>>(W2, B2h, B2l);

    int gblocks = (n + 63) / 64;

    // layer 1: fused aggregate(x fp16, K=128) + GEMM -> fp16 h1
    fused_agg_gemm<IN_DIM, 1><<<gblocks, 256, 0, stream>>>(
        xh, rowptr, ssrc, ewt, dinv, B1h, B1l, b1, h1, nullptr, nullptr, nullptr, n);

    // layer 2: fused aggregate(h1 fp16, K=256) + GEMM + final 256->2 projection
    fused_agg_gemm<HID, 2><<<gblocks, 256, 0, stream>>>(
        h1, rowptr, ssrc, ewt, dinv, B2h, B2l, b2, nullptr, Wl, bl, out, n);
}

// Round 7
// 334.070 us; speedup vs baseline: 1.4360x; 1.4360x over previous
//
#include <hip/hip_runtime.h>
#include <hip/hip_bf16.h>
#include <hip/hip_fp16.h>

constexpr int IN_DIM = 128;
constexpr int HID    = 256;

typedef short  bf16x8 __attribute__((ext_vector_type(8)));
typedef float  f32x4  __attribute__((ext_vector_type(4)));

__device__ inline ushort bf16_rn(float x) {
    uint u = __float_as_uint(x);
    uint r = u + 0x7FFFu + ((u >> 16) & 1u);
    return (ushort)(r >> 16);
}
__device__ inline void split_bf16(float x, ushort& hi, ushort& lo) {
    ushort h = bf16_rn(x);
    float hf = __uint_as_float(((uint)h) << 16);
    hi = h;
    lo = bf16_rn(x - hf);
}

// ---------------- setup kernels ----------------

__global__ void zero_int2(int* __restrict__ a, int* __restrict__ b, int n) {
    int i = blockIdx.x * blockDim.x + threadIdx.x;
    if (i < n) { a[i] = 0; b[i] = 0; }
}

__global__ void count_deg(const int* __restrict__ dst, int* __restrict__ deg, int e) {
    int i = blockIdx.x * blockDim.x + threadIdx.x;
    if (i < e) atomicAdd(&deg[dst[i]], 1);
}

// ---- device-wide exclusive scan of deg -> rowptr; phase 1 also emits dinv ----
__global__ __launch_bounds__(256) void scan_partial(const int* __restrict__ deg,
                                                    int* __restrict__ escan,
                                                    int* __restrict__ blocksum,
                                                    float* __restrict__ dinv, int n) {
    __shared__ int lds[256];
    int t = threadIdx.x;
    int i = blockIdx.x * 256 + t;
    int v = (i < n) ? deg[i] : 0;
    if (i < n) dinv[i] = rsqrtf((float)v + 1.0f);
    lds[t] = v;
    __syncthreads();
    for (int off = 1; off < 256; off <<= 1) {
        int a = lds[t];
        int w = (t >= off) ? lds[t - off] : 0;
        __syncthreads();
        lds[t] = a + w;
        __syncthreads();
    }
    if (i < n) escan[i] = lds[t] - v;
    if (t == 255) blocksum[blockIdx.x] = lds[255];
}

__global__ __launch_bounds__(256) void scan_blocksums(const int* __restrict__ blocksum,
                                                      int* __restrict__ blockoff,
                                                      int nb, int* __restrict__ rowptr_n) {
    __shared__ int lds[256];
    int t = threadIdx.x;
    int v = (t < nb) ? blocksum[t] : 0;
    lds[t] = v;
    __syncthreads();
    for (int off = 1; off < 256; off <<= 1) {
        int a = lds[t];
        int w = (t >= off) ? lds[t - off] : 0;
        __syncthreads();
        lds[t] = a + w;
        __syncthreads();
    }
    if (t < nb) blockoff[t] = lds[t] - v;
    if (t == 255) *rowptr_n = lds[255];
}

__global__ void scan_finalize(const int* __restrict__ escan, const int* __restrict__ blockoff,
                              int* __restrict__ rowptr, int n) {
    int i = blockIdx.x * 256 + threadIdx.x;
    if (i < n) rowptr[i] = escan[i] + blockoff[blockIdx.x];
}

__global__ void scatter_edges(const int* __restrict__ src, const int* __restrict__ dst,
                              const int* __restrict__ rowptr, int* __restrict__ cursor,
                              const float* __restrict__ dinv,
                              int* __restrict__ ssrc, float* __restrict__ ewt, int e) {
    int i = blockIdx.x * blockDim.x + threadIdx.x;
    if (i < e) {
        int d = dst[i];
        int s = src[i];
        int p = atomicAdd(&cursor[d], 1);
        int idx = rowptr[d] + p;
        ssrc[idx] = s;
        ewt[idx]  = dinv[s] * dinv[d];
    }
}

// x fp32 -> fp16
__global__ void convert_x_f16(const float* __restrict__ x, ushort* __restrict__ xh,
                              int total4) {
    int i = blockIdx.x * blockDim.x + threadIdx.x;
    if (i >= total4) return;
    float4 v = *(const float4*)(x + (size_t)i * 4);
    ushort4 o;
    o.x = __half_as_ushort(__float2half(v.x));
    o.y = __half_as_ushort(__float2half(v.y));
    o.z = __half_as_ushort(__float2half(v.z));
    o.w = __half_as_ushort(__float2half(v.w));
    *(ushort4*)(xh + (size_t)i * 4) = o;
}

// ---------------- weight preconvert: B[K][256] fp32 -> hi/lo bf16 panels ----
// layout: [k>>5][n][k&31] (ushort), chunk stride 256*32
template <int K>
__global__ void convert_B(const float* __restrict__ B, ushort* __restrict__ Bh,
                          ushort* __restrict__ Bl) {
    int id = blockIdx.x * 256 + threadIdx.x;
    if (id >= K * 64) return;
    int k  = id >> 6;
    int n4 = (id & 63) * 4;
    float4 v = *(const float4*)(B + (size_t)k * 256 + n4);
    size_t base = (size_t)(k >> 5) * (256 * 32) + (k & 31);
    float vv[4] = {v.x, v.y, v.z, v.w};
#pragma unroll
    for (int c = 0; c < 4; c++) {
        ushort h, l;
        split_bf16(vv[c], h, l);
        Bh[base + (size_t)(n4 + c) * 32] = h;
        Bl[base + (size_t)(n4 + c) * 32] = l;
    }
}

// ---------------- aggregation: one wave per node, fp16 gather --------------
// Writes result as pre-split bf16 hi/lo panels in MFMA layout
// [k>>5][row][k&31], chunk stride Mp*32. Arithmetic identical to fp32 path.
template <int K>  // K halves per row: 128 or 256
__global__ __launch_bounds__(256) void aggregate_p(const ushort* __restrict__ h,
                                                   const int* __restrict__ rowptr,
                                                   const int* __restrict__ ssrc,
                                                   const float* __restrict__ ewt,
                                                   const float* __restrict__ dinv,
                                                   ushort* __restrict__ Ph,
                                                   ushort* __restrict__ Pl,
                                                   int n, int Mp) {
    constexpr int VH = K / 64;  // halves per lane: 2 or 4
    int wid  = (blockIdx.x * 256 + threadIdx.x) >> 6;
    int lane = threadIdx.x & 63;
    if (wid >= n) return;
    float di = dinv[wid];
    float sw = di * di;
    float acc[VH];
    {
        const ushort* row = h + (size_t)wid * K + lane * VH;
        if constexpr (VH == 4) {
            uint2 u = *(const uint2*)row;
            float2 fa = __half22float2(*(__half2*)&u.x);
            float2 fb = __half22float2(*(__half2*)&u.y);
            acc[0] = fa.x * sw; acc[1] = fa.y * sw; acc[2] = fb.x * sw; acc[3] = fb.y * sw;
        } else {
            uint u = *(const uint*)row;
            float2 fa = __half22float2(*(__half2*)&u);
            acc[0] = fa.x * sw; acc[1] = fa.y * sw;
        }
    }
    int beg = rowptr[wid], fin = rowptr[wid + 1];
    for (int b = beg; b < fin; b += 64) {
        int cnt = fin - b;
        if (cnt > 64) cnt = 64;
        int   sv = (lane < cnt) ? ssrc[b + lane] : 0;
        float wv = (lane < cnt) ? ewt[b + lane]  : 0.f;
#pragma unroll 2
        for (int t = 0; t < cnt; t++) {
            int   s = __shfl(sv, t);
            float w = __shfl(wv, t);
            const ushort* r = h + (size_t)s * K + lane * VH;
            if constexpr (VH == 4) {
                uint2 u = *(const uint2*)r;
                float2 fa = __half22float2(*(__half2*)&u.x);
                float2 fb = __half22float2(*(__half2*)&u.y);
                acc[0] += fa.x * w; acc[1] += fa.y * w;
                acc[2] += fb.x * w; acc[3] += fb.y * w;
            } else {
                uint u = *(const uint*)r;
                float2 fa = __half22float2(*(__half2*)&u);
                acc[0] += fa.x * w; acc[1] += fa.y * w;
            }
        }
    }
    // split + write to panel layout
    int kglob = lane * VH;
    int chunk = kglob >> 5;
    int inner = kglob & 31;
    size_t base = (size_t)chunk * Mp * 32 + (size_t)wid * 32 + inner;
    if constexpr (VH == 4) {
        ushort h0, l0, h1, l1, h2, l2, h3, l3;
        split_bf16(acc[0], h0, l0); split_bf16(acc[1], h1, l1);
        split_bf16(acc[2], h2, l2); split_bf16(acc[3], h3, l3);
        *(uint2*)&Ph[base] = make_uint2((uint)h0 | ((uint)h1 << 16), (uint)h2 | ((uint)h3 << 16));
        *(uint2*)&Pl[base] = make_uint2((uint)l0 | ((uint)l1 << 16), (uint)l2 | ((uint)l3 << 16));
    } else {
        ushort h0, l0, h1, l1;
        split_bf16(acc[0], h0, l0); split_bf16(acc[1], h1, l1);
        *(uint*)&Ph[base] = (uint)h0 | ((uint)h1 << 16);
        *(uint*)&Pl[base] = (uint)l0 | ((uint)l1 << 16);
    }
}

// ---------------- panel MFMA GEMM: no LDS, no barriers in K-loop ------------
// A panels [K/32][Mp][32] (hi/lo), B panels [K/32][256][32] (hi/lo).
// Block: 256 thr = 4 waves; BM=64 rows, wave w owns cols [64w, 64w+64).
// MODE 1: C16[M,256] = fp16(relu(A@B + bias))
// MODE 2: out[M,2]  = relu(A@B + bias) @ Wl + bl
template <int K, int MODE>
__global__ __launch_bounds__(256, 2) void gemm_panel(const ushort* __restrict__ Aph,
                                                     const ushort* __restrict__ Apl,
                                                     const ushort* __restrict__ Bh,
                                                     const ushort* __restrict__ Bl,
                                                     const float* __restrict__ bias,
                                                     ushort* __restrict__ C16,
                                                     const float* __restrict__ Wl,
                                                     const float* __restrict__ bl,
                                                     float* __restrict__ out,
                                                     int M, int Mp) {
    __shared__ float part[4][64][2];  // MODE 2 only (2 KB)

    int tid  = threadIdx.x;
    int w    = tid >> 6;
    int lane = tid & 63;
    int l15  = lane & 15;
    int quad = lane >> 4;
    int row0 = blockIdx.x * 64;

    f32x4 acc[4][4] = {};

#pragma unroll
    for (int k0 = 0; k0 < K; k0 += 32) {
        int c = k0 >> 5;
        const ushort* ah = Aph + (size_t)c * Mp * 32;
        const ushort* al = Apl + (size_t)c * Mp * 32;
        const ushort* bh = Bh + (size_t)c * 256 * 32;
        const ushort* bl_ = Bl + (size_t)c * 256 * 32;

        bf16x8 af_h[4], af_l[4], bf_h[4], bf_l[4];
#pragma unroll
        for (int i = 0; i < 4; i++) {
            size_t ro = (size_t)(row0 + i * 16 + l15) * 32 + quad * 8;
            af_h[i] = *(const bf16x8*)(ah + ro);
            af_l[i] = *(const bf16x8*)(al + ro);
        }
#pragma unroll
        for (int j = 0; j < 4; j++) {
            size_t co = (size_t)(w * 64 + j * 16 + l15) * 32 + quad * 8;
            bf_h[j] = *(const bf16x8*)(bh + co);
            bf_l[j] = *(const bf16x8*)(bl_ + co);
        }
#pragma unroll
        for (int i = 0; i < 4; i++)
#pragma unroll
            for (int j = 0; j < 4; j++) {
                acc[i][j] = __builtin_amdgcn_mfma_f32_16x16x32_bf16(af_h[i], bf_h[j], acc[i][j], 0, 0, 0);
                acc[i][j] = __builtin_amdgcn_mfma_f32_16x16x32_bf16(af_h[i], bf_l[j], acc[i][j], 0, 0, 0);
                acc[i][j] = __builtin_amdgcn_mfma_f32_16x16x32_bf16(af_l[i], bf_h[j], acc[i][j], 0, 0, 0);
            }
    }

    float bj[4];
#pragma unroll
    for (int j = 0; j < 4; j++) bj[j] = bias[w * 64 + j * 16 + l15];

    if constexpr (MODE == 1) {
#pragma unroll
        for (int i = 0; i < 4; i++)
#pragma unroll
            for (int reg = 0; reg < 4; reg++) {
                int r = row0 + i * 16 + quad * 4 + reg;
                if (r < M) {
                    ushort* cp = C16 + (size_t)r * 256 + w * 64 + l15;
#pragma unroll
                    for (int j = 0; j < 4; j++) {
                        float v = fmaxf(acc[i][j][reg] + bj[j], 0.f);
                        cp[j * 16] = __half_as_ushort(__float2half(v));
                    }
                }
            }
    } else {
        float wl0[4], wl1[4];
#pragma unroll
        for (int j = 0; j < 4; j++) {
            int cj = w * 64 + j * 16 + l15;
            float2 wv = *(const float2*)(Wl + cj * 2);
            wl0[j] = wv.x; wl1[j] = wv.y;
        }
#pragma unroll
        for (int i = 0; i < 4; i++)
#pragma unroll
            for (int reg = 0; reg < 4; reg++) {
                float s0 = 0.f, s1 = 0.f;
#pragma unroll
                for (int j = 0; j < 4; j++) {
                    float v = fmaxf(acc[i][j][reg] + bj[j], 0.f);
                    s0 += v * wl0[j];
                    s1 += v * wl1[j];
                }
#pragma unroll
                for (int off = 1; off < 16; off <<= 1) {
                    s0 += __shfl_xor(s0, off);
                    s1 += __shfl_xor(s1, off);
                }
                if (l15 == 0) {
                    int r = i * 16 + quad * 4 + reg;
                    part[w][r][0] = s0;
                    part[w][r][1] = s1;
                }
            }
        __syncthreads();
        if (tid < 128) {
            int r = tid >> 1, o = tid & 1;
            int grr = row0 + r;
            if (grr < M) {
                float s = part[0][r][o] + part[1][r][o] + part[2][r][o] + part[3][r][o] + bl[o];
                out[(size_t)grr * 2 + o] = s;
            }
        }
    }
}

// ---------------- launch ----------------

extern "C" void kernel_launch(void* const* d_in, const int* in_sizes, int n_in,
                              void* d_out, int out_size, void* d_ws, size_t ws_size,
                              hipStream_t stream) {
    const float* x  = (const float*)d_in[0];
    const int*   ei = (const int*)d_in[1];
    const float* W1 = (const float*)d_in[2];
    const float* b1 = (const float*)d_in[3];
    const float* W2 = (const float*)d_in[4];
    const float* b2 = (const float*)d_in[5];
    const float* Wl = (const float*)d_in[6];
    const float* bl = (const float*)d_in[7];
    float* out = (float*)d_out;

    int n = in_sizes[0] / IN_DIM;  // 50000
    int e = in_sizes[1] / 2;       // 600000
    const int* src = ei;
    const int* dst = ei + e;

    int gblocks = (n + 63) / 64;
    int Mp = gblocks * 64;         // padded row count for A panels

    char* ws = (char*)d_ws;
    size_t off = 0;
    auto alloc = [&](size_t bytes) -> void* {
        void* p = ws + off;
        off += (bytes + 255) & ~(size_t)255;
        return p;
    };
    int*    deg    = (int*)alloc((size_t)n * 4);
    int*    cursor = (int*)alloc((size_t)n * 4);
    float*  dinv   = (float*)alloc((size_t)n * 4);
    int*    rowptr = (int*)alloc((size_t)(n + 1) * 4);
    int*    escan  = (int*)alloc((size_t)n * 4);
    int*    bsum   = (int*)alloc(256 * 4);
    int*    boff   = (int*)alloc(256 * 4);
    int*    ssrc   = (int*)alloc((size_t)e * 4);
    float*  ewt    = (float*)alloc((size_t)e * 4);
    ushort* xh     = (ushort*)alloc((size_t)n * IN_DIM * 2);
    ushort* h1     = (ushort*)alloc((size_t)n * HID * 2);
    ushort* A1h    = (ushort*)alloc((size_t)Mp * IN_DIM * 2);
    ushort* A1l    = (ushort*)alloc((size_t)Mp * IN_DIM * 2);
    ushort* A2h    = (ushort*)alloc((size_t)Mp * HID * 2);
    ushort* A2l    = (ushort*)alloc((size_t)Mp * HID * 2);
    ushort* B1h    = (ushort*)alloc((size_t)IN_DIM * 256 * 2);
    ushort* B1l    = (ushort*)alloc((size_t)IN_DIM * 256 * 2);
    ushort* B2h    = (ushort*)alloc((size_t)HID * 256 * 2);
    ushort* B2l    = (ushort*)alloc((size_t)HID * 256 * 2);

    int nb = (n + 255) / 256;   // 196 (<= 256 required by scan_blocksums)
    int eb = (e + 255) / 256;

    zero_int2<<<nb, 256, 0, stream>>>(deg, cursor, n);
    count_deg<<<eb, 256, 0, stream>>>(dst, deg, e);

    scan_partial<<<nb, 256, 0, stream>>>(deg, escan, bsum, dinv, n);
    scan_blocksums<<<1, 256, 0, stream>>>(bsum, boff, nb, rowptr + n);
    scan_finalize<<<nb, 256, 0, stream>>>(escan, boff, rowptr, n);

    scatter_edges<<<eb, 256, 0, stream>>>(src, dst, rowptr, cursor, dinv, ssrc, ewt, e);

    int total4 = n * IN_DIM / 4;
    convert_x_f16<<<(total4 + 255) / 256, 256, 0, stream>>>(x, xh, total4);
    convert_B<IN_DIM><<<IN_DIM * 64 / 256, 256, 0, stream>>>(W1, B1h, B1l);
    convert_B<HID><<<HID * 64 / 256, 256, 0, stream>>>(W2, B2h, B2l);

    // layer 1: aggregate fp16 x -> A1 panels, barrier-free panel GEMM -> fp16 h1
    aggregate_p<IN_DIM><<<(n + 3) / 4, 256, 0, stream>>>(xh, rowptr, ssrc, ewt, dinv,
                                                         A1h, A1l, n, Mp);
    gemm_panel<IN_DIM, 1><<<gblocks, 256, 0, stream>>>(A1h, A1l, B1h, B1l, b1, h1,
                                                       nullptr, nullptr, nullptr, n, Mp);

    // layer 2: aggregate fp16 h1 -> A2 panels, panel GEMM + final 256->2 projection
    aggregate_p<HID><<<(n + 3) / 4, 256, 0, stream>>>(h1, rowptr, ssrc, ewt, dinv,
                                                      A2h, A2l, n, Mp);
    gemm_panel<HID, 2><<<gblocks, 256, 0, stream>>>(A2h, A2l, B2h, B2l, b2, nullptr,
                                                    Wl, bl, out, n, Mp);
}

// Round 8
// 332.995 us; speedup vs baseline: 1.4406x; 1.0032x over previous
//
#include <hip/hip_runtime.h>
#include <hip/hip_bf16.h>
#include <hip/hip_fp16.h>

constexpr int IN_DIM = 128;
constexpr int HID    = 256;

typedef short  bf16x8 __attribute__((ext_vector_type(8)));
typedef float  f32x4  __attribute__((ext_vector_type(4)));

__device__ inline ushort bf16_rn(float x) {
    uint u = __float_as_uint(x);
    uint r = u + 0x7FFFu + ((u >> 16) & 1u);
    return (ushort)(r >> 16);
}
__device__ inline void split_bf16(float x, ushort& hi, ushort& lo) {
    ushort h = bf16_rn(x);
    float hf = __uint_as_float(((uint)h) << 16);
    hi = h;
    lo = bf16_rn(x - hf);
}

// ---------------- setup kernels ----------------

__global__ void zero_int2(int* __restrict__ a, int* __restrict__ b, int n) {
    int i = blockIdx.x * blockDim.x + threadIdx.x;
    if (i < n) { a[i] = 0; b[i] = 0; }
}

__global__ void count_deg(const int* __restrict__ dst, int* __restrict__ deg, int e) {
    int i = blockIdx.x * blockDim.x + threadIdx.x;
    if (i < e) atomicAdd(&deg[dst[i]], 1);
}

// ---- device-wide exclusive scan of deg -> rowptr; phase 1 also emits dinv ----
__global__ __launch_bounds__(256) void scan_partial(const int* __restrict__ deg,
                                                    int* __restrict__ escan,
                                                    int* __restrict__ blocksum,
                                                    float* __restrict__ dinv, int n) {
    __shared__ int lds[256];
    int t = threadIdx.x;
    int i = blockIdx.x * 256 + t;
    int v = (i < n) ? deg[i] : 0;
    if (i < n) dinv[i] = rsqrtf((float)v + 1.0f);
    lds[t] = v;
    __syncthreads();
    for (int off = 1; off < 256; off <<= 1) {
        int a = lds[t];
        int w = (t >= off) ? lds[t - off] : 0;
        __syncthreads();
        lds[t] = a + w;
        __syncthreads();
    }
    if (i < n) escan[i] = lds[t] - v;
    if (t == 255) blocksum[blockIdx.x] = lds[255];
}

__global__ __launch_bounds__(256) void scan_blocksums(const int* __restrict__ blocksum,
                                                      int* __restrict__ blockoff,
                                                      int nb, int* __restrict__ rowptr_n) {
    __shared__ int lds[256];
    int t = threadIdx.x;
    int v = (t < nb) ? blocksum[t] : 0;
    lds[t] = v;
    __syncthreads();
    for (int off = 1; off < 256; off <<= 1) {
        int a = lds[t];
        int w = (t >= off) ? lds[t - off] : 0;
        __syncthreads();
        lds[t] = a + w;
        __syncthreads();
    }
    if (t < nb) blockoff[t] = lds[t] - v;
    if (t == 255) *rowptr_n = lds[255];
}

__global__ void scan_finalize(const int* __restrict__ escan, const int* __restrict__ blockoff,
                              int* __restrict__ rowptr, int n) {
    int i = blockIdx.x * 256 + threadIdx.x;
    if (i < n) rowptr[i] = escan[i] + blockoff[blockIdx.x];
}

__global__ void scatter_edges(const int* __restrict__ src, const int* __restrict__ dst,
                              const int* __restrict__ rowptr, int* __restrict__ cursor,
                              const float* __restrict__ dinv,
                              int* __restrict__ ssrc, float* __restrict__ ewt, int e) {
    int i = blockIdx.x * blockDim.x + threadIdx.x;
    if (i < e) {
        int d = dst[i];
        int s = src[i];
        int p = atomicAdd(&cursor[d], 1);
        int idx = rowptr[d] + p;
        ssrc[idx] = s;
        ewt[idx]  = dinv[s] * dinv[d];
    }
}

// x fp32 -> fp16
__global__ void convert_x_f16(const float* __restrict__ x, ushort* __restrict__ xh,
                              int total4) {
    int i = blockIdx.x * blockDim.x + threadIdx.x;
    if (i >= total4) return;
    float4 v = *(const float4*)(x + (size_t)i * 4);
    ushort4 o;
    o.x = __half_as_ushort(__float2half(v.x));
    o.y = __half_as_ushort(__float2half(v.y));
    o.z = __half_as_ushort(__float2half(v.z));
    o.w = __half_as_ushort(__float2half(v.w));
    *(ushort4*)(xh + (size_t)i * 4) = o;
}

// ---------------- weight preconvert: B[K][256] fp32 -> hi/lo bf16 panels ----
// layout: [k>>5][n][k&31] (ushort), chunk stride 256*32
template <int K>
__global__ void convert_B(const float* __restrict__ B, ushort* __restrict__ Bh,
                          ushort* __restrict__ Bl) {
    int id = blockIdx.x * 256 + threadIdx.x;
    if (id >= K * 64) return;
    int k  = id >> 6;
    int n4 = (id & 63) * 4;
    float4 v = *(const float4*)(B + (size_t)k * 256 + n4);
    size_t base = (size_t)(k >> 5) * (256 * 32) + (k & 31);
    float vv[4] = {v.x, v.y, v.z, v.w};
#pragma unroll
    for (int c = 0; c < 4; c++) {
        ushort h, l;
        split_bf16(vv[c], h, l);
        Bh[base + (size_t)(n4 + c) * 32] = h;
        Bl[base + (size_t)(n4 + c) * 32] = l;
    }
}

// ---------------- aggregation: one wave per node, fp16 gather --------------
// Writes result as pre-split bf16 hi/lo panels in MFMA layout
// [k>>5][row][k&31], chunk stride Mp*32.
template <int K>  // K halves per row: 128 or 256
__global__ __launch_bounds__(256) void aggregate_p(const ushort* __restrict__ h,
                                                   const int* __restrict__ rowptr,
                                                   const int* __restrict__ ssrc,
                                                   const float* __restrict__ ewt,
                                                   const float* __restrict__ dinv,
                                                   ushort* __restrict__ Ph,
                                                   ushort* __restrict__ Pl,
                                                   int n, int Mp) {
    constexpr int VH = K / 64;  // halves per lane: 2 or 4
    int wid  = (blockIdx.x * 256 + threadIdx.x) >> 6;
    int lane = threadIdx.x & 63;
    if (wid >= n) return;
    float di = dinv[wid];
    float sw = di * di;
    float acc[VH];
    {
        const ushort* row = h + (size_t)wid * K + lane * VH;
        if constexpr (VH == 4) {
            uint2 u = *(const uint2*)row;
            float2 fa = __half22float2(*(__half2*)&u.x);
            float2 fb = __half22float2(*(__half2*)&u.y);
            acc[0] = fa.x * sw; acc[1] = fa.y * sw; acc[2] = fb.x * sw; acc[3] = fb.y * sw;
        } else {
            uint u = *(const uint*)row;
            float2 fa = __half22float2(*(__half2*)&u);
            acc[0] = fa.x * sw; acc[1] = fa.y * sw;
        }
    }
    int beg = rowptr[wid], fin = rowptr[wid + 1];
    for (int b = beg; b < fin; b += 64) {
        int cnt = fin - b;
        if (cnt > 64) cnt = 64;
        int   sv = (lane < cnt) ? ssrc[b + lane] : 0;
        float wv = (lane < cnt) ? ewt[b + lane]  : 0.f;
#pragma unroll 2
        for (int t = 0; t < cnt; t++) {
            int   s = __shfl(sv, t);
            float w = __shfl(wv, t);
            const ushort* r = h + (size_t)s * K + lane * VH;
            if constexpr (VH == 4) {
                uint2 u = *(const uint2*)r;
                float2 fa = __half22float2(*(__half2*)&u.x);
                float2 fb = __half22float2(*(__half2*)&u.y);
                acc[0] += fa.x * w; acc[1] += fa.y * w;
                acc[2] += fb.x * w; acc[3] += fb.y * w;
            } else {
                uint u = *(const uint*)r;
                float2 fa = __half22float2(*(__half2*)&u);
                acc[0] += fa.x * w; acc[1] += fa.y * w;
            }
        }
    }
    int kglob = lane * VH;
    int chunk = kglob >> 5;
    int inner = kglob & 31;
    size_t base = (size_t)chunk * Mp * 32 + (size_t)wid * 32 + inner;
    if constexpr (VH == 4) {
        ushort h0, l0, h1, l1, h2, l2, h3, l3;
        split_bf16(acc[0], h0, l0); split_bf16(acc[1], h1, l1);
        split_bf16(acc[2], h2, l2); split_bf16(acc[3], h3, l3);
        *(uint2*)&Ph[base] = make_uint2((uint)h0 | ((uint)h1 << 16), (uint)h2 | ((uint)h3 << 16));
        *(uint2*)&Pl[base] = make_uint2((uint)l0 | ((uint)l1 << 16), (uint)l2 | ((uint)l3 << 16));
    } else {
        ushort h0, l0, h1, l1;
        split_bf16(acc[0], h0, l0); split_bf16(acc[1], h1, l1);
        *(uint*)&Ph[base] = (uint)h0 | ((uint)h1 << 16);
        *(uint*)&Pl[base] = (uint)l0 | ((uint)l1 << 16);
    }
}

// ---------------- panel MFMA GEMM: no LDS/barriers, reg double-buffered ----
// A panels [K/32][Mp][32] (hi/lo), B panels [K/32][256][32] (hi/lo).
// Block: 256 thr = 4 waves; BM=64 rows, wave w owns cols [64w, 64w+64).
// K-loop prefetches chunk c+1's 16 fragments while doing chunk c's 48 MFMAs.
// MODE 1: C16[M,256] = fp16(relu(A@B + bias))
// MODE 2: out[M,2]  = relu(A@B + bias) @ Wl + bl
template <int K, int MODE>
__global__ __launch_bounds__(256, 2) void gemm_panel(const ushort* __restrict__ Aph,
                                                     const ushort* __restrict__ Apl,
                                                     const ushort* __restrict__ Bh,
                                                     const ushort* __restrict__ Bl,
                                                     const float* __restrict__ bias,
                                                     ushort* __restrict__ C16,
                                                     const float* __restrict__ Wl,
                                                     const float* __restrict__ bl,
                                                     float* __restrict__ out,
                                                     int M, int Mp) {
    constexpr int NC = K / 32;
    __shared__ float part[4][64][2];  // MODE 2 only (2 KB)

    int tid  = threadIdx.x;
    int w    = tid >> 6;
    int lane = tid & 63;
    int l15  = lane & 15;
    int quad = lane >> 4;
    int row0 = blockIdx.x * 64;

    // per-lane fragment offsets (constant across chunks)
    size_t aro[4], bco[4];
#pragma unroll
    for (int i = 0; i < 4; i++) aro[i] = (size_t)(row0 + i * 16 + l15) * 32 + quad * 8;
#pragma unroll
    for (int j = 0; j < 4; j++) bco[j] = (size_t)(w * 64 + j * 16 + l15) * 32 + quad * 8;

    bf16x8 fa_h[2][4], fa_l[2][4], fb_h[2][4], fb_l[2][4];

    auto load_chunk = [&](int c, int buf) {
        const ushort* ah  = Aph + (size_t)c * Mp * 32;
        const ushort* al  = Apl + (size_t)c * Mp * 32;
        const ushort* bh  = Bh  + (size_t)c * 256 * 32;
        const ushort* bl_ = Bl  + (size_t)c * 256 * 32;
#pragma unroll
        for (int i = 0; i < 4; i++) {
            fa_h[buf][i] = *(const bf16x8*)(ah + aro[i]);
            fa_l[buf][i] = *(const bf16x8*)(al + aro[i]);
        }
#pragma unroll
        for (int j = 0; j < 4; j++) {
            fb_h[buf][j] = *(const bf16x8*)(bh + bco[j]);
            fb_l[buf][j] = *(const bf16x8*)(bl_ + bco[j]);
        }
    };

    f32x4 acc[4][4] = {};

    load_chunk(0, 0);
#pragma unroll
    for (int c = 0; c < NC; c++) {
        int cur = c & 1;
        if (c + 1 < NC) load_chunk(c + 1, cur ^ 1);
#pragma unroll
        for (int i = 0; i < 4; i++)
#pragma unroll
            for (int j = 0; j < 4; j++) {
                acc[i][j] = __builtin_amdgcn_mfma_f32_16x16x32_bf16(fa_h[cur][i], fb_h[cur][j], acc[i][j], 0, 0, 0);
                acc[i][j] = __builtin_amdgcn_mfma_f32_16x16x32_bf16(fa_h[cur][i], fb_l[cur][j], acc[i][j], 0, 0, 0);
                acc[i][j] = __builtin_amdgcn_mfma_f32_16x16x32_bf16(fa_l[cur][i], fb_h[cur][j], acc[i][j], 0, 0, 0);
            }
    }

    float bj[4];
#pragma unroll
    for (int j = 0; j < 4; j++) bj[j] = bias[w * 64 + j * 16 + l15];

    if constexpr (MODE == 1) {
#pragma unroll
        for (int i = 0; i < 4; i++)
#pragma unroll
            for (int reg = 0; reg < 4; reg++) {
                int r = row0 + i * 16 + quad * 4 + reg;
                if (r < M) {
                    ushort* cp = C16 + (size_t)r * 256 + w * 64 + l15;
#pragma unroll
                    for (int j = 0; j < 4; j++) {
                        float v = fmaxf(acc[i][j][reg] + bj[j], 0.f);
                        cp[j * 16] = __half_as_ushort(__float2half(v));
                    }
                }
            }
    } else {
        float wl0[4], wl1[4];
#pragma unroll
        for (int j = 0; j < 4; j++) {
            int cj = w * 64 + j * 16 + l15;
            float2 wv = *(const float2*)(Wl + cj * 2);
            wl0[j] = wv.x; wl1[j] = wv.y;
        }
#pragma unroll
        for (int i = 0; i < 4; i++)
#pragma unroll
            for (int reg = 0; reg < 4; reg++) {
                float s0 = 0.f, s1 = 0.f;
#pragma unroll
                for (int j = 0; j < 4; j++) {
                    float v = fmaxf(acc[i][j][reg] + bj[j], 0.f);
                    s0 += v * wl0[j];
                    s1 += v * wl1[j];
                }
#pragma unroll
                for (int off = 1; off < 16; off <<= 1) {
                    s0 += __shfl_xor(s0, off);
                    s1 += __shfl_xor(s1, off);
                }
                if (l15 == 0) {
                    int r = i * 16 + quad * 4 + reg;
                    part[w][r][0] = s0;
                    part[w][r][1] = s1;
                }
            }
        __syncthreads();
        if (tid < 128) {
            int r = tid >> 1, o = tid & 1;
            int grr = row0 + r;
            if (grr < M) {
                float s = part[0][r][o] + part[1][r][o] + part[2][r][o] + part[3][r][o] + bl[o];
                out[(size_t)grr * 2 + o] = s;
            }
        }
    }
}

// ---------------- launch ----------------

extern "C" void kernel_launch(void* const* d_in, const int* in_sizes, int n_in,
                              void* d_out, int out_size, void* d_ws, size_t ws_size,
                              hipStream_t stream) {
    const float* x  = (const float*)d_in[0];
    const int*   ei = (const int*)d_in[1];
    const float* W1 = (const float*)d_in[2];
    const float* b1 = (const float*)d_in[3];
    const float* W2 = (const float*)d_in[4];
    const float* b2 = (const float*)d_in[5];
    const float* Wl = (const float*)d_in[6];
    const float* bl = (const float*)d_in[7];
    float* out = (float*)d_out;

    int n = in_sizes[0] / IN_DIM;  // 50000
    int e = in_sizes[1] / 2;       // 600000
    const int* src = ei;
    const int* dst = ei + e;

    int gblocks = (n + 63) / 64;
    int Mp = gblocks * 64;         // padded row count for A panels

    char* ws = (char*)d_ws;
    size_t off = 0;
    auto alloc = [&](size_t bytes) -> void* {
        void* p = ws + off;
        off += (bytes + 255) & ~(size_t)255;
        return p;
    };
    int*    deg    = (int*)alloc((size_t)n * 4);
    int*    cursor = (int*)alloc((size_t)n * 4);
    float*  dinv   = (float*)alloc((size_t)n * 4);
    int*    rowptr = (int*)alloc((size_t)(n + 1) * 4);
    int*    escan  = (int*)alloc((size_t)n * 4);
    int*    bsum   = (int*)alloc(256 * 4);
    int*    boff   = (int*)alloc(256 * 4);
    int*    ssrc   = (int*)alloc((size_t)e * 4);
    float*  ewt    = (float*)alloc((size_t)e * 4);
    ushort* xh     = (ushort*)alloc((size_t)n * IN_DIM * 2);
    ushort* h1     = (ushort*)alloc((size_t)n * HID * 2);
    ushort* A1h    = (ushort*)alloc((size_t)Mp * IN_DIM * 2);
    ushort* A1l    = (ushort*)alloc((size_t)Mp * IN_DIM * 2);
    ushort* A2h    = (ushort*)alloc((size_t)Mp * HID * 2);
    ushort* A2l    = (ushort*)alloc((size_t)Mp * HID * 2);
    ushort* B1h    = (ushort*)alloc((size_t)IN_DIM * 256 * 2);
    ushort* B1l    = (ushort*)alloc((size_t)IN_DIM * 256 * 2);
    ushort* B2h    = (ushort*)alloc((size_t)HID * 256 * 2);
    ushort* B2l    = (ushort*)alloc((size_t)HID * 256 * 2);

    int nb = (n + 255) / 256;   // 196 (<= 256 required by scan_blocksums)
    int eb = (e + 255) / 256;

    zero_int2<<<nb, 256, 0, stream>>>(deg, cursor, n);
    count_deg<<<eb, 256, 0, stream>>>(dst, deg, e);

    scan_partial<<<nb, 256, 0, stream>>>(deg, escan, bsum, dinv, n);
    scan_blocksums<<<1, 256, 0, stream>>>(bsum, boff, nb, rowptr + n);
    scan_finalize<<<nb, 256, 0, stream>>>(escan, boff, rowptr, n);

    scatter_edges<<<eb, 256, 0, stream>>>(src, dst, rowptr, cursor, dinv, ssrc, ewt, e);

    int total4 = n * IN_DIM / 4;
    convert_x_f16<<<(total4 + 255) / 256, 256, 0, stream>>>(x, xh, total4);
    convert_B<IN_DIM><<<IN_DIM * 64 / 256, 256, 0, stream>>>(W1, B1h, B1l);
    convert_B<HID><<<HID * 64 / 256, 256, 0, stream>>>(W2, B2h, B2l);

    // layer 1: aggregate fp16 x -> A1 panels, prefetched panel GEMM -> fp16 h1
    aggregate_p<IN_DIM><<<(n + 3) / 4, 256, 0, stream>>>(xh, rowptr, ssrc, ewt, dinv,
                                                         A1h, A1l, n, Mp);
    gemm_panel<IN_DIM, 1><<<gblocks, 256, 0, stream>>>(A1h, A1l, B1h, B1l, b1, h1,
                                                       nullptr, nullptr, nullptr, n, Mp);

    // layer 2: aggregate fp16 h1 -> A2 panels, panel GEMM + final 256->2 projection
    aggregate_p<HID><<<(n + 3) / 4, 256, 0, stream>>>(h1, rowptr, ssrc, ewt, dinv,
                                                      A2h, A2l, n, Mp);
    gemm_panel<HID, 2><<<gblocks, 256, 0, stream>>>(A2h, A2l, B2h, B2l, b2, nullptr,
                                                    Wl, bl, out, n, Mp);
}

// Round 9
// 312.904 us; speedup vs baseline: 1.5331x; 1.0642x over previous
//
#include <hip/hip_runtime.h>
#include <hip/hip_bf16.h>
#include <hip/hip_fp16.h>

constexpr int IN_DIM = 128;
constexpr int HID    = 256;

typedef short  bf16x8 __attribute__((ext_vector_type(8)));
typedef float  f32x4  __attribute__((ext_vector_type(4)));

__device__ inline ushort bf16_rn(float x) {
    uint u = __float_as_uint(x);
    uint r = u + 0x7FFFu + ((u >> 16) & 1u);
    return (ushort)(r >> 16);
}
__device__ inline void split_bf16(float x, ushort& hi, ushort& lo) {
    ushort h = bf16_rn(x);
    float hf = __uint_as_float(((uint)h) << 16);
    hi = h;
    lo = bf16_rn(x - hf);
}

// ---------------- setup kernels ----------------

__global__ void zero_int2(int* __restrict__ a, int* __restrict__ b, int n) {
    int i = blockIdx.x * blockDim.x + threadIdx.x;
    if (i < n) { a[i] = 0; b[i] = 0; }
}

__global__ void count_deg(const int* __restrict__ dst, int* __restrict__ deg, int e) {
    int i = blockIdx.x * blockDim.x + threadIdx.x;
    if (i < e) atomicAdd(&deg[dst[i]], 1);
}

// ---- device-wide exclusive scan of deg -> rowptr; phase 1 also emits dinv ----
__global__ __launch_bounds__(256) void scan_partial(const int* __restrict__ deg,
                                                    int* __restrict__ escan,
                                                    int* __restrict__ blocksum,
                                                    float* __restrict__ dinv, int n) {
    __shared__ int lds[256];
    int t = threadIdx.x;
    int i = blockIdx.x * 256 + t;
    int v = (i < n) ? deg[i] : 0;
    if (i < n) dinv[i] = rsqrtf((float)v + 1.0f);
    lds[t] = v;
    __syncthreads();
    for (int off = 1; off < 256; off <<= 1) {
        int a = lds[t];
        int w = (t >= off) ? lds[t - off] : 0;
        __syncthreads();
        lds[t] = a + w;
        __syncthreads();
    }
    if (i < n) escan[i] = lds[t] - v;
    if (t == 255) blocksum[blockIdx.x] = lds[255];
}

__global__ __launch_bounds__(256) void scan_blocksums(const int* __restrict__ blocksum,
                                                      int* __restrict__ blockoff,
                                                      int nb, int* __restrict__ rowptr_n) {
    __shared__ int lds[256];
    int t = threadIdx.x;
    int v = (t < nb) ? blocksum[t] : 0;
    lds[t] = v;
    __syncthreads();
    for (int off = 1; off < 256; off <<= 1) {
        int a = lds[t];
        int w = (t >= off) ? lds[t - off] : 0;
        __syncthreads();
        lds[t] = a + w;
        __syncthreads();
    }
    if (t < nb) blockoff[t] = lds[t] - v;
    if (t == 255) *rowptr_n = lds[255];
}

__global__ void scan_finalize(const int* __restrict__ escan, const int* __restrict__ blockoff,
                              int* __restrict__ rowptr, int n) {
    int i = blockIdx.x * 256 + threadIdx.x;
    if (i < n) rowptr[i] = escan[i] + blockoff[blockIdx.x];
}

__global__ void scatter_edges(const int* __restrict__ src, const int* __restrict__ dst,
                              const int* __restrict__ rowptr, int* __restrict__ cursor,
                              const float* __restrict__ dinv,
                              int* __restrict__ ssrc, float* __restrict__ ewt, int e) {
    int i = blockIdx.x * blockDim.x + threadIdx.x;
    if (i < e) {
        int d = dst[i];
        int s = src[i];
        int p = atomicAdd(&cursor[d], 1);
        int idx = rowptr[d] + p;
        ssrc[idx] = s;
        ewt[idx]  = dinv[s] * dinv[d];
    }
}

// x fp32 -> fp16
__global__ void convert_x_f16(const float* __restrict__ x, ushort* __restrict__ xh,
                              int total4) {
    int i = blockIdx.x * blockDim.x + threadIdx.x;
    if (i >= total4) return;
    float4 v = *(const float4*)(x + (size_t)i * 4);
    ushort4 o;
    o.x = __half_as_ushort(__float2half(v.x));
    o.y = __half_as_ushort(__float2half(v.y));
    o.z = __half_as_ushort(__float2half(v.z));
    o.w = __half_as_ushort(__float2half(v.w));
    *(ushort4*)(xh + (size_t)i * 4) = o;
}

// ---------------- weight preconvert: B[K][256] fp32 -> hi/lo bf16 panels ----
// layout: [k>>5][n][k&31] (ushort), chunk stride 256*32
template <int K>
__global__ void convert_B(const float* __restrict__ B, ushort* __restrict__ Bh,
                          ushort* __restrict__ Bl) {
    int id = blockIdx.x * 256 + threadIdx.x;
    if (id >= K * 64) return;
    int k  = id >> 6;
    int n4 = (id & 63) * 4;
    float4 v = *(const float4*)(B + (size_t)k * 256 + n4);
    size_t base = (size_t)(k >> 5) * (256 * 32) + (k & 31);
    float vv[4] = {v.x, v.y, v.z, v.w};
#pragma unroll
    for (int c = 0; c < 4; c++) {
        ushort h, l;
        split_bf16(vv[c], h, l);
        Bh[base + (size_t)(n4 + c) * 32] = h;
        Bl[base + (size_t)(n4 + c) * 32] = l;
    }
}

// ---------------- aggregation: one wave per node, fp16 gather --------------
// Writes result as pre-split bf16 hi/lo panels in MFMA layout
// [k>>5][row][k&31], chunk stride Mp*32.
template <int K>  // K halves per row: 128 or 256
__global__ __launch_bounds__(256) void aggregate_p(const ushort* __restrict__ h,
                                                   const int* __restrict__ rowptr,
                                                   const int* __restrict__ ssrc,
                                                   const float* __restrict__ ewt,
                                                   const float* __restrict__ dinv,
                                                   ushort* __restrict__ Ph,
                                                   ushort* __restrict__ Pl,
                                                   int n, int Mp) {
    constexpr int VH = K / 64;  // halves per lane: 2 or 4
    int wid  = (blockIdx.x * 256 + threadIdx.x) >> 6;
    int lane = threadIdx.x & 63;
    if (wid >= n) return;
    float di = dinv[wid];
    float sw = di * di;
    float acc[VH];
    {
        const ushort* row = h + (size_t)wid * K + lane * VH;
        if constexpr (VH == 4) {
            uint2 u = *(const uint2*)row;
            float2 fa = __half22float2(*(__half2*)&u.x);
            float2 fb = __half22float2(*(__half2*)&u.y);
            acc[0] = fa.x * sw; acc[1] = fa.y * sw; acc[2] = fb.x * sw; acc[3] = fb.y * sw;
        } else {
            uint u = *(const uint*)row;
            float2 fa = __half22float2(*(__half2*)&u);
            acc[0] = fa.x * sw; acc[1] = fa.y * sw;
        }
    }
    int beg = rowptr[wid], fin = rowptr[wid + 1];
    for (int b = beg; b < fin; b += 64) {
        int cnt = fin - b;
        if (cnt > 64) cnt = 64;
        int   sv = (lane < cnt) ? ssrc[b + lane] : 0;
        float wv = (lane < cnt) ? ewt[b + lane]  : 0.f;
#pragma unroll 2
        for (int t = 0; t < cnt; t++) {
            int   s = __shfl(sv, t);
            float w = __shfl(wv, t);
            const ushort* r = h + (size_t)s * K + lane * VH;
            if constexpr (VH == 4) {
                uint2 u = *(const uint2*)r;
                float2 fa = __half22float2(*(__half2*)&u.x);
                float2 fb = __half22float2(*(__half2*)&u.y);
                acc[0] += fa.x * w; acc[1] += fa.y * w;
                acc[2] += fb.x * w; acc[3] += fb.y * w;
            } else {
                uint u = *(const uint*)r;
                float2 fa = __half22float2(*(__half2*)&u);
                acc[0] += fa.x * w; acc[1] += fa.y * w;
            }
        }
    }
    int kglob = lane * VH;
    int chunk = kglob >> 5;
    int inner = kglob & 31;
    size_t base = (size_t)chunk * Mp * 32 + (size_t)wid * 32 + inner;
    if constexpr (VH == 4) {
        ushort h0, l0, h1, l1, h2, l2, h3, l3;
        split_bf16(acc[0], h0, l0); split_bf16(acc[1], h1, l1);
        split_bf16(acc[2], h2, l2); split_bf16(acc[3], h3, l3);
        *(uint2*)&Ph[base] = make_uint2((uint)h0 | ((uint)h1 << 16), (uint)h2 | ((uint)h3 << 16));
        *(uint2*)&Pl[base] = make_uint2((uint)l0 | ((uint)l1 << 16), (uint)l2 | ((uint)l3 << 16));
    } else {
        ushort h0, l0, h1, l1;
        split_bf16(acc[0], h0, l0); split_bf16(acc[1], h1, l1);
        *(uint*)&Ph[base] = (uint)h0 | ((uint)h1 << 16);
        *(uint*)&Pl[base] = (uint)l0 | ((uint)l1 << 16);
    }
}

// ---------------- MFMA GEMM: A via async DMA to LDS, B streamed ------------
// A panels [K/32][Mp][32] (hi/lo): block DMAs its whole 64-row A tile to LDS
// up front with global_load_lds (deep async queue -> bytes-bound), one barrier,
// then a barrier-free K-loop: A frags via ds_read_b128, B frags from global
// (L2-hot: B is 128-512 KB shared by all blocks).
// MODE 1: C16[M,256] = fp16(relu(A@B + bias))
// MODE 2: out[M,2]  = relu(A@B + bias) @ Wl + bl
template <int K, int MODE>
__global__ __launch_bounds__(256, 2) void gemm_alds(const ushort* __restrict__ Aph,
                                                    const ushort* __restrict__ Apl,
                                                    const ushort* __restrict__ Bh,
                                                    const ushort* __restrict__ Bl,
                                                    const float* __restrict__ bias,
                                                    ushort* __restrict__ C16,
                                                    const float* __restrict__ Wl,
                                                    const float* __restrict__ bl,
                                                    float* __restrict__ out,
                                                    int M, int Mp) {
    constexpr int NC = K / 32;
    __shared__ ushort Ah[NC * 2048];   // [chunk][row 0..63][inner 0..31]
    __shared__ ushort Al[NC * 2048];
    __shared__ float part[4][64][2];   // MODE 2 only

    int tid  = threadIdx.x;
    int w    = tid >> 6;
    int lane = tid & 63;
    int l15  = lane & 15;
    int quad = lane >> 4;
    int row0 = blockIdx.x * 64;

    // ---- async DMA: whole A tile (hi+lo, all chunks) into LDS ----
    // inst j: chunk c=j>>3, sub=j&7 (0-3 hi rowgroups, 4-7 lo rowgroups);
    // each inst copies 1 KB (16 rows x 64 B) contiguously, lane i -> +16 B.
    constexpr int TOT = NC * 8;
    for (int j = w; j < TOT; j += 4) {
        int c   = j >> 3;
        int sub = j & 7;
        const ushort* g = ((sub < 4) ? Aph : Apl) +
                          (size_t)c * Mp * 32 + (size_t)(row0 + (sub & 3) * 16) * 32;
        ushort* l = ((sub < 4) ? Ah : Al) + c * 2048 + (sub & 3) * 512;
        __builtin_amdgcn_global_load_lds(
            (const __attribute__((address_space(1))) uint*)(g + (size_t)lane * 8),
            (__attribute__((address_space(3))) uint*)l, 16, 0, 0);
    }
    __syncthreads();  // drains vmcnt -> all A resident in LDS

    // per-lane B fragment offsets (constant across chunks)
    size_t bco[4];
#pragma unroll
    for (int j = 0; j < 4; j++) bco[j] = (size_t)(w * 64 + j * 16 + l15) * 32 + quad * 8;

    bf16x8 fb_h[2][4], fb_l[2][4];
    auto loadB = [&](int c, int buf) {
        const ushort* bh  = Bh + (size_t)c * 256 * 32;
        const ushort* bl_ = Bl + (size_t)c * 256 * 32;
#pragma unroll
        for (int j = 0; j < 4; j++) {
            fb_h[buf][j] = *(const bf16x8*)(bh + bco[j]);
            fb_l[buf][j] = *(const bf16x8*)(bl_ + bco[j]);
        }
    };

    f32x4 acc[4][4] = {};
    loadB(0, 0);
#pragma unroll
    for (int c = 0; c < NC; c++) {
        int cur = c & 1;
        if (c + 1 < NC) loadB(c + 1, cur ^ 1);
        bf16x8 fa_h[4], fa_l[4];
#pragma unroll
        for (int i = 0; i < 4; i++) {
            int off = c * 2048 + (i * 16 + l15) * 32 + quad * 8;
            fa_h[i] = *(const bf16x8*)&Ah[off];
            fa_l[i] = *(const bf16x8*)&Al[off];
        }
#pragma unroll
        for (int i = 0; i < 4; i++)
#pragma unroll
            for (int j = 0; j < 4; j++) {
                acc[i][j] = __builtin_amdgcn_mfma_f32_16x16x32_bf16(fa_h[i], fb_h[cur][j], acc[i][j], 0, 0, 0);
                acc[i][j] = __builtin_amdgcn_mfma_f32_16x16x32_bf16(fa_h[i], fb_l[cur][j], acc[i][j], 0, 0, 0);
                acc[i][j] = __builtin_amdgcn_mfma_f32_16x16x32_bf16(fa_l[i], fb_h[cur][j], acc[i][j], 0, 0, 0);
            }
    }

    float bj[4];
#pragma unroll
    for (int j = 0; j < 4; j++) bj[j] = bias[w * 64 + j * 16 + l15];

    if constexpr (MODE == 1) {
#pragma unroll
        for (int i = 0; i < 4; i++)
#pragma unroll
            for (int reg = 0; reg < 4; reg++) {
                int r = row0 + i * 16 + quad * 4 + reg;
                if (r < M) {
                    ushort* cp = C16 + (size_t)r * 256 + w * 64 + l15;
#pragma unroll
                    for (int j = 0; j < 4; j++) {
                        float v = fmaxf(acc[i][j][reg] + bj[j], 0.f);
                        cp[j * 16] = __half_as_ushort(__float2half(v));
                    }
                }
            }
    } else {
        float wl0[4], wl1[4];
#pragma unroll
        for (int j = 0; j < 4; j++) {
            int cj = w * 64 + j * 16 + l15;
            float2 wv = *(const float2*)(Wl + cj * 2);
            wl0[j] = wv.x; wl1[j] = wv.y;
        }
#pragma unroll
        for (int i = 0; i < 4; i++)
#pragma unroll
            for (int reg = 0; reg < 4; reg++) {
                float s0 = 0.f, s1 = 0.f;
#pragma unroll
                for (int j = 0; j < 4; j++) {
                    float v = fmaxf(acc[i][j][reg] + bj[j], 0.f);
                    s0 += v * wl0[j];
                    s1 += v * wl1[j];
                }
#pragma unroll
                for (int off = 1; off < 16; off <<= 1) {
                    s0 += __shfl_xor(s0, off);
                    s1 += __shfl_xor(s1, off);
                }
                if (l15 == 0) {
                    int r = i * 16 + quad * 4 + reg;
                    part[w][r][0] = s0;
                    part[w][r][1] = s1;
                }
            }
        __syncthreads();
        if (tid < 128) {
            int r = tid >> 1, o = tid & 1;
            int grr = row0 + r;
            if (grr < M) {
                float s = part[0][r][o] + part[1][r][o] + part[2][r][o] + part[3][r][o] + bl[o];
                out[(size_t)grr * 2 + o] = s;
            }
        }
    }
}

// ---------------- launch ----------------

extern "C" void kernel_launch(void* const* d_in, const int* in_sizes, int n_in,
                              void* d_out, int out_size, void* d_ws, size_t ws_size,
                              hipStream_t stream) {
    const float* x  = (const float*)d_in[0];
    const int*   ei = (const int*)d_in[1];
    const float* W1 = (const float*)d_in[2];
    const float* b1 = (const float*)d_in[3];
    const float* W2 = (const float*)d_in[4];
    const float* b2 = (const float*)d_in[5];
    const float* Wl = (const float*)d_in[6];
    const float* bl = (const float*)d_in[7];
    float* out = (float*)d_out;

    int n = in_sizes[0] / IN_DIM;  // 50000
    int e = in_sizes[1] / 2;       // 600000
    const int* src = ei;
    const int* dst = ei + e;

    int gblocks = (n + 63) / 64;
    int Mp = gblocks * 64;         // padded row count for A panels

    char* ws = (char*)d_ws;
    size_t off = 0;
    auto alloc = [&](size_t bytes) -> void* {
        void* p = ws + off;
        off += (bytes + 255) & ~(size_t)255;
        return p;
    };
    int*    deg    = (int*)alloc((size_t)n * 4);
    int*    cursor = (int*)alloc((size_t)n * 4);
    float*  dinv   = (float*)alloc((size_t)n * 4);
    int*    rowptr = (int*)alloc((size_t)(n + 1) * 4);
    int*    escan  = (int*)alloc((size_t)n * 4);
    int*    bsum   = (int*)alloc(256 * 4);
    int*    boff   = (int*)alloc(256 * 4);
    int*    ssrc   = (int*)alloc((size_t)e * 4);
    float*  ewt    = (float*)alloc((size_t)e * 4);
    ushort* xh     = (ushort*)alloc((size_t)n * IN_DIM * 2);
    ushort* h1     = (ushort*)alloc((size_t)n * HID * 2);
    ushort* A1h    = (ushort*)alloc((size_t)Mp * IN_DIM * 2);
    ushort* A1l    = (ushort*)alloc((size_t)Mp * IN_DIM * 2);
    ushort* A2h    = (ushort*)alloc((size_t)Mp * HID * 2);
    ushort* A2l    = (ushort*)alloc((size_t)Mp * HID * 2);
    ushort* B1h    = (ushort*)alloc((size_t)IN_DIM * 256 * 2);
    ushort* B1l    = (ushort*)alloc((size_t)IN_DIM * 256 * 2);
    ushort* B2h    = (ushort*)alloc((size_t)HID * 256 * 2);
    ushort* B2l    = (ushort*)alloc((size_t)HID * 256 * 2);

    int nb = (n + 255) / 256;   // 196 (<= 256 required by scan_blocksums)
    int eb = (e + 255) / 256;

    zero_int2<<<nb, 256, 0, stream>>>(deg, cursor, n);
    count_deg<<<eb, 256, 0, stream>>>(dst, deg, e);

    scan_partial<<<nb, 256, 0, stream>>>(deg, escan, bsum, dinv, n);
    scan_blocksums<<<1, 256, 0, stream>>>(bsum, boff, nb, rowptr + n);
    scan_finalize<<<nb, 256, 0, stream>>>(escan, boff, rowptr, n);

    scatter_edges<<<eb, 256, 0, stream>>>(src, dst, rowptr, cursor, dinv, ssrc, ewt, e);

    int total4 = n * IN_DIM / 4;
    convert_x_f16<<<(total4 + 255) / 256, 256, 0, stream>>>(x, xh, total4);
    convert_B<IN_DIM><<<IN_DIM * 64 / 256, 256, 0, stream>>>(W1, B1h, B1l);
    convert_B<HID><<<HID * 64 / 256, 256, 0, stream>>>(W2, B2h, B2l);

    // layer 1: aggregate fp16 x -> A1 panels, async-LDS panel GEMM -> fp16 h1
    aggregate_p<IN_DIM><<<(n + 3) / 4, 256, 0, stream>>>(xh, rowptr, ssrc, ewt, dinv,
                                                         A1h, A1l, n, Mp);
    gemm_alds<IN_DIM, 1><<<gblocks, 256, 0, stream>>>(A1h, A1l, B1h, B1l, b1, h1,
                                                      nullptr, nullptr, nullptr, n, Mp);

    // layer 2: aggregate fp16 h1 -> A2 panels, async-LDS GEMM + final projection
    aggregate_p<HID><<<(n + 3) / 4, 256, 0, stream>>>(h1, rowptr, ssrc, ewt, dinv,
                                                      A2h, A2l, n, Mp);
    gemm_alds<HID, 2><<<gblocks, 256, 0, stream>>>(A2h, A2l, B2h, B2l, b2, nullptr,
                                                   Wl, bl, out, n, Mp);
}

// Round 10
// 292.052 us; speedup vs baseline: 1.6426x; 1.0714x over previous
//
#include <hip/hip_runtime.h>
#include <hip/hip_bf16.h>
#include <hip/hip_fp16.h>

constexpr int IN_DIM = 128;
constexpr int HID    = 256;

typedef _Float16 f16x8 __attribute__((ext_vector_type(8)));
typedef float    f32x4 __attribute__((ext_vector_type(4)));

// ---------------- setup kernels ----------------

__global__ void zero_int2(int* __restrict__ a, int* __restrict__ b, int n) {
    int i = blockIdx.x * blockDim.x + threadIdx.x;
    if (i < n) { a[i] = 0; b[i] = 0; }
}

__global__ void count_deg(const int* __restrict__ dst, int* __restrict__ deg, int e) {
    int i = blockIdx.x * blockDim.x + threadIdx.x;
    if (i < e) atomicAdd(&deg[dst[i]], 1);
}

// ---- device-wide exclusive scan of deg -> rowptr; phase 1 also emits dinv ----
__global__ __launch_bounds__(256) void scan_partial(const int* __restrict__ deg,
                                                    int* __restrict__ escan,
                                                    int* __restrict__ blocksum,
                                                    float* __restrict__ dinv, int n) {
    __shared__ int lds[256];
    int t = threadIdx.x;
    int i = blockIdx.x * 256 + t;
    int v = (i < n) ? deg[i] : 0;
    if (i < n) dinv[i] = rsqrtf((float)v + 1.0f);
    lds[t] = v;
    __syncthreads();
    for (int off = 1; off < 256; off <<= 1) {
        int a = lds[t];
        int w = (t >= off) ? lds[t - off] : 0;
        __syncthreads();
        lds[t] = a + w;
        __syncthreads();
    }
    if (i < n) escan[i] = lds[t] - v;
    if (t == 255) blocksum[blockIdx.x] = lds[255];
}

__global__ __launch_bounds__(256) void scan_blocksums(const int* __restrict__ blocksum,
                                                      int* __restrict__ blockoff,
                                                      int nb, int* __restrict__ rowptr_n) {
    __shared__ int lds[256];
    int t = threadIdx.x;
    int v = (t < nb) ? blocksum[t] : 0;
    lds[t] = v;
    __syncthreads();
    for (int off = 1; off < 256; off <<= 1) {
        int a = lds[t];
        int w = (t >= off) ? lds[t - off] : 0;
        __syncthreads();
        lds[t] = a + w;
        __syncthreads();
    }
    if (t < nb) blockoff[t] = lds[t] - v;
    if (t == 255) *rowptr_n = lds[255];
}

__global__ void scan_finalize(const int* __restrict__ escan, const int* __restrict__ blockoff,
                              int* __restrict__ rowptr, int n) {
    int i = blockIdx.x * 256 + threadIdx.x;
    if (i < n) rowptr[i] = escan[i] + blockoff[blockIdx.x];
}

__global__ void scatter_edges(const int* __restrict__ src, const int* __restrict__ dst,
                              const int* __restrict__ rowptr, int* __restrict__ cursor,
                              const float* __restrict__ dinv,
                              int* __restrict__ ssrc, float* __restrict__ ewt, int e) {
    int i = blockIdx.x * blockDim.x + threadIdx.x;
    if (i < e) {
        int d = dst[i];
        int s = src[i];
        int p = atomicAdd(&cursor[d], 1);
        int idx = rowptr[d] + p;
        ssrc[idx] = s;
        ewt[idx]  = dinv[s] * dinv[d];
    }
}

// x fp32 -> fp16
__global__ void convert_x_f16(const float* __restrict__ x, ushort* __restrict__ xh,
                              int total4) {
    int i = blockIdx.x * blockDim.x + threadIdx.x;
    if (i >= total4) return;
    float4 v = *(const float4*)(x + (size_t)i * 4);
    ushort4 o;
    o.x = __half_as_ushort(__float2half(v.x));
    o.y = __half_as_ushort(__float2half(v.y));
    o.z = __half_as_ushort(__float2half(v.z));
    o.w = __half_as_ushort(__float2half(v.w));
    *(ushort4*)(xh + (size_t)i * 4) = o;
}

// ---------------- weight preconvert: B[K][256] fp32 -> fp16 panel ----------
// layout: [k>>5][n][k&31] (fp16), chunk stride 256*32
template <int K>
__global__ void convert_B_h(const float* __restrict__ B, ushort* __restrict__ Bp) {
    int id = blockIdx.x * 256 + threadIdx.x;
    if (id >= K * 64) return;
    int k  = id >> 6;
    int n4 = (id & 63) * 4;
    float4 v = *(const float4*)(B + (size_t)k * 256 + n4);
    size_t base = (size_t)(k >> 5) * (256 * 32) + (k & 31);
    Bp[base + (size_t)(n4 + 0) * 32] = __half_as_ushort(__float2half(v.x));
    Bp[base + (size_t)(n4 + 1) * 32] = __half_as_ushort(__float2half(v.y));
    Bp[base + (size_t)(n4 + 2) * 32] = __half_as_ushort(__float2half(v.z));
    Bp[base + (size_t)(n4 + 3) * 32] = __half_as_ushort(__float2half(v.w));
}

// ---------------- aggregation: one wave per node, fp16 gather --------------
// fp32 accum; writes result as fp16 panel in MFMA layout [k>>5][row][k&31],
// chunk stride Mp*32.
template <int K>  // K halves per row: 128 or 256
__global__ __launch_bounds__(256) void aggregate_p(const ushort* __restrict__ h,
                                                   const int* __restrict__ rowptr,
                                                   const int* __restrict__ ssrc,
                                                   const float* __restrict__ ewt,
                                                   const float* __restrict__ dinv,
                                                   ushort* __restrict__ Pp,
                                                   int n, int Mp) {
    constexpr int VH = K / 64;  // halves per lane: 2 or 4
    int wid  = (blockIdx.x * 256 + threadIdx.x) >> 6;
    int lane = threadIdx.x & 63;
    if (wid >= n) return;
    float di = dinv[wid];
    float sw = di * di;
    float acc[VH];
    {
        const ushort* row = h + (size_t)wid * K + lane * VH;
        if constexpr (VH == 4) {
            uint2 u = *(const uint2*)row;
            float2 fa = __half22float2(*(__half2*)&u.x);
            float2 fb = __half22float2(*(__half2*)&u.y);
            acc[0] = fa.x * sw; acc[1] = fa.y * sw; acc[2] = fb.x * sw; acc[3] = fb.y * sw;
        } else {
            uint u = *(const uint*)row;
            float2 fa = __half22float2(*(__half2*)&u);
            acc[0] = fa.x * sw; acc[1] = fa.y * sw;
        }
    }
    int beg = rowptr[wid], fin = rowptr[wid + 1];
    for (int b = beg; b < fin; b += 64) {
        int cnt = fin - b;
        if (cnt > 64) cnt = 64;
        int   sv = (lane < cnt) ? ssrc[b + lane] : 0;
        float wv = (lane < cnt) ? ewt[b + lane]  : 0.f;
#pragma unroll 2
        for (int t = 0; t < cnt; t++) {
            int   s = __shfl(sv, t);
            float w = __shfl(wv, t);
            const ushort* r = h + (size_t)s * K + lane * VH;
            if constexpr (VH == 4) {
                uint2 u = *(const uint2*)r;
                float2 fa = __half22float2(*(__half2*)&u.x);
                float2 fb = __half22float2(*(__half2*)&u.y);
                acc[0] += fa.x * w; acc[1] += fa.y * w;
                acc[2] += fb.x * w; acc[3] += fb.y * w;
            } else {
                uint u = *(const uint*)r;
                float2 fa = __half22float2(*(__half2*)&u);
                acc[0] += fa.x * w; acc[1] += fa.y * w;
            }
        }
    }
    int kglob = lane * VH;
    int chunk = kglob >> 5;
    int inner = kglob & 31;
    size_t base = (size_t)chunk * Mp * 32 + (size_t)wid * 32 + inner;
    if constexpr (VH == 4) {
        __half2 p0 = __floats2half2_rn(acc[0], acc[1]);
        __half2 p1 = __floats2half2_rn(acc[2], acc[3]);
        *(uint2*)&Pp[base] = make_uint2(*(uint*)&p0, *(uint*)&p1);
    } else {
        __half2 p0 = __floats2half2_rn(acc[0], acc[1]);
        *(uint*)&Pp[base] = *(uint*)&p0;
    }
}

// ---------------- fp16 MFMA GEMM: A via async DMA to LDS, B streamed -------
// A panel [K/32][Mp][32] fp16: block DMAs its 64-row A tile (K*64*2 = 16/32 KB)
// to LDS up front (deep async queue), one barrier, then barrier-free K-loop:
// A frags via ds_read_b128, B fp16 frags from global (L2-hot, double-buffered).
// MODE 1: C16[M,256] = fp16(relu(A@B + bias))
// MODE 2: out[M,2]  = relu(A@B + bias) @ Wl + bl
template <int K, int MODE>
__global__ __launch_bounds__(256, 2) void gemm_f16(const ushort* __restrict__ Ap,
                                                   const ushort* __restrict__ Bp,
                                                   const float* __restrict__ bias,
                                                   ushort* __restrict__ C16,
                                                   const float* __restrict__ Wl,
                                                   const float* __restrict__ bl,
                                                   float* __restrict__ out,
                                                   int M, int Mp) {
    constexpr int NC = K / 32;
    __shared__ ushort Asm[NC * 2048];  // [chunk][row 0..63][inner 0..31] fp16
    __shared__ float part[4][64][2];   // MODE 2 only

    int tid  = threadIdx.x;
    int w    = tid >> 6;
    int lane = tid & 63;
    int l15  = lane & 15;
    int quad = lane >> 4;
    int row0 = blockIdx.x * 64;

    // ---- async DMA: whole A tile into LDS (1 KB per inst: 16 rows x 64 B) ----
    constexpr int TOT = NC * 4;
    for (int j = w; j < TOT; j += 4) {
        int c   = j >> 2;
        int sub = j & 3;
        const ushort* g = Ap + (size_t)c * Mp * 32 + (size_t)(row0 + sub * 16) * 32;
        ushort* l = Asm + c * 2048 + sub * 512;
        __builtin_amdgcn_global_load_lds(
            (const __attribute__((address_space(1))) uint*)(g + (size_t)lane * 8),
            (__attribute__((address_space(3))) uint*)l, 16, 0, 0);
    }
    __syncthreads();  // drains vmcnt -> all A resident in LDS

    // per-lane B fragment offsets (constant across chunks)
    size_t bco[4];
#pragma unroll
    for (int j = 0; j < 4; j++) bco[j] = (size_t)(w * 64 + j * 16 + l15) * 32 + quad * 8;

    f16x8 fb[2][4];
    auto loadB = [&](int c, int buf) {
        const ushort* bp = Bp + (size_t)c * 256 * 32;
#pragma unroll
        for (int j = 0; j < 4; j++) fb[buf][j] = *(const f16x8*)(bp + bco[j]);
    };

    f32x4 acc[4][4] = {};
    loadB(0, 0);
#pragma unroll
    for (int c = 0; c < NC; c++) {
        int cur = c & 1;
        if (c + 1 < NC) loadB(c + 1, cur ^ 1);
        f16x8 fa[4];
#pragma unroll
        for (int i = 0; i < 4; i++) {
            int off = c * 2048 + (i * 16 + l15) * 32 + quad * 8;
            fa[i] = *(const f16x8*)&Asm[off];
        }
#pragma unroll
        for (int i = 0; i < 4; i++)
#pragma unroll
            for (int j = 0; j < 4; j++)
                acc[i][j] = __builtin_amdgcn_mfma_f32_16x16x32_f16(fa[i], fb[cur][j], acc[i][j], 0, 0, 0);
    }

    float bj[4];
#pragma unroll
    for (int j = 0; j < 4; j++) bj[j] = bias[w * 64 + j * 16 + l15];

    if constexpr (MODE == 1) {
#pragma unroll
        for (int i = 0; i < 4; i++)
#pragma unroll
            for (int reg = 0; reg < 4; reg++) {
                int r = row0 + i * 16 + quad * 4 + reg;
                if (r < M) {
                    ushort* cp = C16 + (size_t)r * 256 + w * 64 + l15;
#pragma unroll
                    for (int j = 0; j < 4; j++) {
                        float v = fmaxf(acc[i][j][reg] + bj[j], 0.f);
                        cp[j * 16] = __half_as_ushort(__float2half(v));
                    }
                }
            }
    } else {
        float wl0[4], wl1[4];
#pragma unroll
        for (int j = 0; j < 4; j++) {
            int cj = w * 64 + j * 16 + l15;
            float2 wv = *(const float2*)(Wl + cj * 2);
            wl0[j] = wv.x; wl1[j] = wv.y;
        }
#pragma unroll
        for (int i = 0; i < 4; i++)
#pragma unroll
            for (int reg = 0; reg < 4; reg++) {
                float s0 = 0.f, s1 = 0.f;
#pragma unroll
                for (int j = 0; j < 4; j++) {
                    float v = fmaxf(acc[i][j][reg] + bj[j], 0.f);
                    s0 += v * wl0[j];
                    s1 += v * wl1[j];
                }
#pragma unroll
                for (int off = 1; off < 16; off <<= 1) {
                    s0 += __shfl_xor(s0, off);
                    s1 += __shfl_xor(s1, off);
                }
                if (l15 == 0) {
                    int r = i * 16 + quad * 4 + reg;
                    part[w][r][0] = s0;
                    part[w][r][1] = s1;
                }
            }
        __syncthreads();
        if (tid < 128) {
            int r = tid >> 1, o = tid & 1;
            int grr = row0 + r;
            if (grr < M) {
                float s = part[0][r][o] + part[1][r][o] + part[2][r][o] + part[3][r][o] + bl[o];
                out[(size_t)grr * 2 + o] = s;
            }
        }
    }
}

// ---------------- launch ----------------

extern "C" void kernel_launch(void* const* d_in, const int* in_sizes, int n_in,
                              void* d_out, int out_size, void* d_ws, size_t ws_size,
                              hipStream_t stream) {
    const float* x  = (const float*)d_in[0];
    const int*   ei = (const int*)d_in[1];
    const float* W1 = (const float*)d_in[2];
    const float* b1 = (const float*)d_in[3];
    const float* W2 = (const float*)d_in[4];
    const float* b2 = (const float*)d_in[5];
    const float* Wl = (const float*)d_in[6];
    const float* bl = (const float*)d_in[7];
    float* out = (float*)d_out;

    int n = in_sizes[0] / IN_DIM;  // 50000
    int e = in_sizes[1] / 2;       // 600000
    const int* src = ei;
    const int* dst = ei + e;

    int gblocks = (n + 63) / 64;
    int Mp = gblocks * 64;         // padded row count for A panels

    char* ws = (char*)d_ws;
    size_t off = 0;
    auto alloc = [&](size_t bytes) -> void* {
        void* p = ws + off;
        off += (bytes + 255) & ~(size_t)255;
        return p;
    };
    int*    deg    = (int*)alloc((size_t)n * 4);
    int*    cursor = (int*)alloc((size_t)n * 4);
    float*  dinv   = (float*)alloc((size_t)n * 4);
    int*    rowptr = (int*)alloc((size_t)(n + 1) * 4);
    int*    escan  = (int*)alloc((size_t)n * 4);
    int*    bsum   = (int*)alloc(256 * 4);
    int*    boff   = (int*)alloc(256 * 4);
    int*    ssrc   = (int*)alloc((size_t)e * 4);
    float*  ewt    = (float*)alloc((size_t)e * 4);
    ushort* xh     = (ushort*)alloc((size_t)n * IN_DIM * 2);
    ushort* h1     = (ushort*)alloc((size_t)n * HID * 2);
    ushort* A1p    = (ushort*)alloc((size_t)Mp * IN_DIM * 2);
    ushort* A2p    = (ushort*)alloc((size_t)Mp * HID * 2);
    ushort* B1p    = (ushort*)alloc((size_t)IN_DIM * 256 * 2);
    ushort* B2p    = (ushort*)alloc((size_t)HID * 256 * 2);

    int nb = (n + 255) / 256;   // 196 (<= 256 required by scan_blocksums)
    int eb = (e + 255) / 256;

    zero_int2<<<nb, 256, 0, stream>>>(deg, cursor, n);
    count_deg<<<eb, 256, 0, stream>>>(dst, deg, e);

    scan_partial<<<nb, 256, 0, stream>>>(deg, escan, bsum, dinv, n);
    scan_blocksums<<<1, 256, 0, stream>>>(bsum, boff, nb, rowptr + n);
    scan_finalize<<<nb, 256, 0, stream>>>(escan, boff, rowptr, n);

    scatter_edges<<<eb, 256, 0, stream>>>(src, dst, rowptr, cursor, dinv, ssrc, ewt, e);

    int total4 = n * IN_DIM / 4;
    convert_x_f16<<<(total4 + 255) / 256, 256, 0, stream>>>(x, xh, total4);
    convert_B_h<IN_DIM><<<IN_DIM * 64 / 256, 256, 0, stream>>>(W1, B1p);
    convert_B_h<HID><<<HID * 64 / 256, 256, 0, stream>>>(W2, B2p);

    // layer 1: aggregate fp16 x -> A1 panel, fp16-MFMA GEMM -> fp16 h1
    aggregate_p<IN_DIM><<<(n + 3) / 4, 256, 0, stream>>>(xh, rowptr, ssrc, ewt, dinv,
                                                         A1p, n, Mp);
    gemm_f16<IN_DIM, 1><<<gblocks, 256, 0, stream>>>(A1p, B1p, b1, h1,
                                                     nullptr, nullptr, nullptr, n, Mp);

    // layer 2: aggregate fp16 h1 -> A2 panel, fp16-MFMA GEMM + final projection
    aggregate_p<HID><<<(n + 3) / 4, 256, 0, stream>>>(h1, rowptr, ssrc, ewt, dinv,
                                                      A2p, n, Mp);
    gemm_f16<HID, 2><<<gblocks, 256, 0, stream>>>(A2p, B2p, b2, nullptr,
                                                  Wl, bl, out, n, Mp);
}

// Round 11
// 282.662 us; speedup vs baseline: 1.6971x; 1.0332x over previous
//
#include <hip/hip_runtime.h>
#include <hip/hip_bf16.h>
#include <hip/hip_fp16.h>

constexpr int IN_DIM = 128;
constexpr int HID    = 256;

typedef _Float16 f16x8 __attribute__((ext_vector_type(8)));
typedef float    f32x4 __attribute__((ext_vector_type(4)));

// ---------------- setup kernels ----------------

__global__ void zero_int2(int* __restrict__ a, int* __restrict__ b, int n) {
    int i = blockIdx.x * blockDim.x + threadIdx.x;
    if (i < n) { a[i] = 0; b[i] = 0; }
}

__global__ void count_deg(const int* __restrict__ dst, int* __restrict__ deg, int e) {
    int i = blockIdx.x * blockDim.x + threadIdx.x;
    if (i < e) atomicAdd(&deg[dst[i]], 1);
}

// ---- scan phase 1: per-block inclusive scan + block total; also emits dinv ----
__global__ __launch_bounds__(256) void scan_partial(const int* __restrict__ deg,
                                                    int* __restrict__ escan,
                                                    int* __restrict__ blocksum,
                                                    float* __restrict__ dinv, int n) {
    __shared__ int lds[256];
    int t = threadIdx.x;
    int i = blockIdx.x * 256 + t;
    int v = (i < n) ? deg[i] : 0;
    if (i < n) dinv[i] = rsqrtf((float)v + 1.0f);
    lds[t] = v;
    __syncthreads();
    for (int off = 1; off < 256; off <<= 1) {
        int a = lds[t];
        int w = (t >= off) ? lds[t - off] : 0;
        __syncthreads();
        lds[t] = a + w;
        __syncthreads();
    }
    if (i < n) escan[i] = lds[t] - v;   // exclusive within block
    if (t == 255) blocksum[blockIdx.x] = lds[255];
}

// ---- scan phases 2+3 fused: every block redundantly scans blocksums (nb<=256)
// in LDS, takes its own offset, finalizes its 256 rowptr entries ----
__global__ __launch_bounds__(256) void scan_rest(const int* __restrict__ escan,
                                                 const int* __restrict__ blocksum,
                                                 int nb, int* __restrict__ rowptr, int n) {
    __shared__ int lds[256];
    int t = threadIdx.x;
    int v = (t < nb) ? blocksum[t] : 0;
    lds[t] = v;
    __syncthreads();
    for (int off = 1; off < 256; off <<= 1) {
        int a = lds[t];
        int w = (t >= off) ? lds[t - off] : 0;
        __syncthreads();
        lds[t] = a + w;
        __syncthreads();
    }
    int boff = (blockIdx.x > 0) ? lds[blockIdx.x - 1] : 0;
    int i = blockIdx.x * 256 + t;
    if (i < n) rowptr[i] = escan[i] + boff;
    if (blockIdx.x == 0 && t == 0) rowptr[n] = lds[nb - 1];
}

__global__ void scatter_edges(const int* __restrict__ src, const int* __restrict__ dst,
                              const int* __restrict__ rowptr, int* __restrict__ cursor,
                              const float* __restrict__ dinv,
                              int* __restrict__ ssrc, float* __restrict__ ewt, int e) {
    int i = blockIdx.x * blockDim.x + threadIdx.x;
    if (i < e) {
        int d = dst[i];
        int s = src[i];
        int p = atomicAdd(&cursor[d], 1);
        int idx = rowptr[d] + p;
        ssrc[idx] = s;
        ewt[idx]  = dinv[s] * dinv[d];
    }
}

// ---- fused input conversion: W1 -> B1 panel, W2 -> B2 panel, x -> fp16 ----
// panel layout: [k>>5][n][k&31] fp16, chunk stride 256*32
__device__ inline void conv_B_elem(const float* B, ushort* Bp, int id, int /*K*/) {
    int k  = id >> 6;
    int n4 = (id & 63) * 4;
    float4 v = *(const float4*)(B + (size_t)k * 256 + n4);
    size_t base = (size_t)(k >> 5) * (256 * 32) + (k & 31);
    Bp[base + (size_t)(n4 + 0) * 32] = __half_as_ushort(__float2half(v.x));
    Bp[base + (size_t)(n4 + 1) * 32] = __half_as_ushort(__float2half(v.y));
    Bp[base + (size_t)(n4 + 2) * 32] = __half_as_ushort(__float2half(v.z));
    Bp[base + (size_t)(n4 + 3) * 32] = __half_as_ushort(__float2half(v.w));
}

__global__ void convert_inputs(const float* __restrict__ W1, ushort* __restrict__ B1p,
                               const float* __restrict__ W2, ushort* __restrict__ B2p,
                               const float* __restrict__ x, ushort* __restrict__ xh,
                               int total4) {
    int id = blockIdx.x * 256 + threadIdx.x;
    if (id < IN_DIM * 64) {
        conv_B_elem(W1, B1p, id, IN_DIM);
    } else if (id < IN_DIM * 64 + HID * 64) {
        conv_B_elem(W2, B2p, id - IN_DIM * 64, HID);
    } else {
        int i = id - (IN_DIM * 64 + HID * 64);
        if (i < total4) {
            float4 v = *(const float4*)(x + (size_t)i * 4);
            ushort4 o;
            o.x = __half_as_ushort(__float2half(v.x));
            o.y = __half_as_ushort(__float2half(v.y));
            o.z = __half_as_ushort(__float2half(v.z));
            o.w = __half_as_ushort(__float2half(v.w));
            *(ushort4*)(xh + (size_t)i * 4) = o;
        }
    }
}

// ---------------- aggregation: one wave per node, fp16 gather --------------
// fp32 accum; writes result as fp16 panel in MFMA layout [k>>5][row][k&31],
// chunk stride Mp*32.
template <int K>  // K halves per row: 128 or 256
__global__ __launch_bounds__(256) void aggregate_p(const ushort* __restrict__ h,
                                                   const int* __restrict__ rowptr,
                                                   const int* __restrict__ ssrc,
                                                   const float* __restrict__ ewt,
                                                   const float* __restrict__ dinv,
                                                   ushort* __restrict__ Pp,
                                                   int n, int Mp) {
    constexpr int VH = K / 64;  // halves per lane: 2 or 4
    int wid  = (blockIdx.x * 256 + threadIdx.x) >> 6;
    int lane = threadIdx.x & 63;
    if (wid >= n) return;
    float di = dinv[wid];
    float sw = di * di;
    float acc[VH];
    {
        const ushort* row = h + (size_t)wid * K + lane * VH;
        if constexpr (VH == 4) {
            uint2 u = *(const uint2*)row;
            float2 fa = __half22float2(*(__half2*)&u.x);
            float2 fb = __half22float2(*(__half2*)&u.y);
            acc[0] = fa.x * sw; acc[1] = fa.y * sw; acc[2] = fb.x * sw; acc[3] = fb.y * sw;
        } else {
            uint u = *(const uint*)row;
            float2 fa = __half22float2(*(__half2*)&u);
            acc[0] = fa.x * sw; acc[1] = fa.y * sw;
        }
    }
    int beg = rowptr[wid], fin = rowptr[wid + 1];
    for (int b = beg; b < fin; b += 64) {
        int cnt = fin - b;
        if (cnt > 64) cnt = 64;
        int   sv = (lane < cnt) ? ssrc[b + lane] : 0;
        float wv = (lane < cnt) ? ewt[b + lane]  : 0.f;
#pragma unroll 2
        for (int t = 0; t < cnt; t++) {
            int   s = __shfl(sv, t);
            float w = __shfl(wv, t);
            const ushort* r = h + (size_t)s * K + lane * VH;
            if constexpr (VH == 4) {
                uint2 u = *(const uint2*)r;
                float2 fa = __half22float2(*(__half2*)&u.x);
                float2 fb = __half22float2(*(__half2*)&u.y);
                acc[0] += fa.x * w; acc[1] += fa.y * w;
                acc[2] += fb.x * w; acc[3] += fb.y * w;
            } else {
                uint u = *(const uint*)r;
                float2 fa = __half22float2(*(__half2*)&u);
                acc[0] += fa.x * w; acc[1] += fa.y * w;
            }
        }
    }
    int kglob = lane * VH;
    int chunk = kglob >> 5;
    int inner = kglob & 31;
    size_t base = (size_t)chunk * Mp * 32 + (size_t)wid * 32 + inner;
    if constexpr (VH == 4) {
        __half2 p0 = __floats2half2_rn(acc[0], acc[1]);
        __half2 p1 = __floats2half2_rn(acc[2], acc[3]);
        *(uint2*)&Pp[base] = make_uint2(*(uint*)&p0, *(uint*)&p1);
    } else {
        __half2 p0 = __floats2half2_rn(acc[0], acc[1]);
        *(uint*)&Pp[base] = *(uint*)&p0;
    }
}

// ---------------- fp16 MFMA GEMM, BM=32 for 2x TLP -------------------------
// A panel [K/32][Mp][32] fp16: block DMAs its 32-row A tile (K*32*2 = 8/16 KB)
// to LDS up front (async queue), one barrier, then barrier-free K-loop:
// A frags via ds_read_b128, B fp16 frags from global (L2-hot, double-buffered).
// BM=32 -> 1563 blocks (~6/CU) for latency hiding; launch_bounds(256,4) caps
// VGPR at 128 so 4 blocks/CU are resource-feasible.
// MODE 1: C16[M,256] = fp16(relu(A@B + bias))
// MODE 2: out[M,2]  = relu(A@B + bias) @ Wl + bl
template <int K, int MODE>
__global__ __launch_bounds__(256, 4) void gemm_f16(const ushort* __restrict__ Ap,
                                                   const ushort* __restrict__ Bp,
                                                   const float* __restrict__ bias,
                                                   ushort* __restrict__ C16,
                                                   const float* __restrict__ Wl,
                                                   const float* __restrict__ bl,
                                                   float* __restrict__ out,
                                                   int M, int Mp) {
    constexpr int NC = K / 32;
    __shared__ ushort Asm[NC * 1024];  // [chunk][row 0..31][inner 0..31] fp16
    __shared__ float part[4][32][2];   // MODE 2 only

    int tid  = threadIdx.x;
    int w    = tid >> 6;
    int lane = tid & 63;
    int l15  = lane & 15;
    int quad = lane >> 4;
    int row0 = blockIdx.x * 32;

    // ---- async DMA: whole 32-row A tile into LDS (1 KB per inst) ----
    constexpr int TOT = NC * 2;
    for (int j = w; j < TOT; j += 4) {
        int c   = j >> 1;
        int sub = j & 1;
        const ushort* g = Ap + (size_t)c * Mp * 32 + (size_t)(row0 + sub * 16) * 32;
        ushort* l = Asm + c * 1024 + sub * 512;
        __builtin_amdgcn_global_load_lds(
            (const __attribute__((address_space(1))) uint*)(g + (size_t)lane * 8),
            (__attribute__((address_space(3))) uint*)l, 16, 0, 0);
    }
    __syncthreads();  // drains vmcnt -> all A resident in LDS

    // per-lane B fragment offsets (constant across chunks)
    size_t bco[4];
#pragma unroll
    for (int j = 0; j < 4; j++) bco[j] = (size_t)(w * 64 + j * 16 + l15) * 32 + quad * 8;

    f16x8 fb[2][4];
    auto loadB = [&](int c, int buf) {
        const ushort* bp = Bp + (size_t)c * 256 * 32;
#pragma unroll
        for (int j = 0; j < 4; j++) fb[buf][j] = *(const f16x8*)(bp + bco[j]);
    };

    f32x4 acc[2][4] = {};
    loadB(0, 0);
#pragma unroll
    for (int c = 0; c < NC; c++) {
        int cur = c & 1;
        if (c + 1 < NC) loadB(c + 1, cur ^ 1);
        f16x8 fa[2];
#pragma unroll
        for (int i = 0; i < 2; i++) {
            int off = c * 1024 + (i * 16 + l15) * 32 + quad * 8;
            fa[i] = *(const f16x8*)&Asm[off];
        }
#pragma unroll
        for (int i = 0; i < 2; i++)
#pragma unroll
            for (int j = 0; j < 4; j++)
                acc[i][j] = __builtin_amdgcn_mfma_f32_16x16x32_f16(fa[i], fb[cur][j], acc[i][j], 0, 0, 0);
    }

    float bj[4];
#pragma unroll
    for (int j = 0; j < 4; j++) bj[j] = bias[w * 64 + j * 16 + l15];

    if constexpr (MODE == 1) {
#pragma unroll
        for (int i = 0; i < 2; i++)
#pragma unroll
            for (int reg = 0; reg < 4; reg++) {
                int r = row0 + i * 16 + quad * 4 + reg;
                if (r < M) {
                    ushort* cp = C16 + (size_t)r * 256 + w * 64 + l15;
#pragma unroll
                    for (int j = 0; j < 4; j++) {
                        float v = fmaxf(acc[i][j][reg] + bj[j], 0.f);
                        cp[j * 16] = __half_as_ushort(__float2half(v));
                    }
                }
            }
    } else {
        float wl0[4], wl1[4];
#pragma unroll
        for (int j = 0; j < 4; j++) {
            int cj = w * 64 + j * 16 + l15;
            float2 wv = *(const float2*)(Wl + cj * 2);
            wl0[j] = wv.x; wl1[j] = wv.y;
        }
#pragma unroll
        for (int i = 0; i < 2; i++)
#pragma unroll
            for (int reg = 0; reg < 4; reg++) {
                float s0 = 0.f, s1 = 0.f;
#pragma unroll
                for (int j = 0; j < 4; j++) {
                    float v = fmaxf(acc[i][j][reg] + bj[j], 0.f);
                    s0 += v * wl0[j];
                    s1 += v * wl1[j];
                }
#pragma unroll
                for (int off = 1; off < 16; off <<= 1) {
                    s0 += __shfl_xor(s0, off);
                    s1 += __shfl_xor(s1, off);
                }
                if (l15 == 0) {
                    int r = i * 16 + quad * 4 + reg;
                    part[w][r][0] = s0;
                    part[w][r][1] = s1;
                }
            }
        __syncthreads();
        if (tid < 64) {
            int r = tid >> 1, o = tid & 1;
            int grr = row0 + r;
            if (grr < M) {
                float s = part[0][r][o] + part[1][r][o] + part[2][r][o] + part[3][r][o] + bl[o];
                out[(size_t)grr * 2 + o] = s;
            }
        }
    }
}

// ---------------- launch ----------------

extern "C" void kernel_launch(void* const* d_in, const int* in_sizes, int n_in,
                              void* d_out, int out_size, void* d_ws, size_t ws_size,
                              hipStream_t stream) {
    const float* x  = (const float*)d_in[0];
    const int*   ei = (const int*)d_in[1];
    const float* W1 = (const float*)d_in[2];
    const float* b1 = (const float*)d_in[3];
    const float* W2 = (const float*)d_in[4];
    const float* b2 = (const float*)d_in[5];
    const float* Wl = (const float*)d_in[6];
    const float* bl = (const float*)d_in[7];
    float* out = (float*)d_out;

    int n = in_sizes[0] / IN_DIM;  // 50000
    int e = in_sizes[1] / 2;       // 600000
    const int* src = ei;
    const int* dst = ei + e;

    int gblocks = (n + 31) / 32;   // BM=32
    int Mp = gblocks * 32;         // padded row count for A panels

    char* ws = (char*)d_ws;
    size_t off = 0;
    auto alloc = [&](size_t bytes) -> void* {
        void* p = ws + off;
        off += (bytes + 255) & ~(size_t)255;
        return p;
    };
    int*    deg    = (int*)alloc((size_t)n * 4);
    int*    cursor = (int*)alloc((size_t)n * 4);
    float*  dinv   = (float*)alloc((size_t)n * 4);
    int*    rowptr = (int*)alloc((size_t)(n + 1) * 4);
    int*    escan  = (int*)alloc((size_t)n * 4);
    int*    bsum   = (int*)alloc(256 * 4);
    int*    ssrc   = (int*)alloc((size_t)e * 4);
    float*  ewt    = (float*)alloc((size_t)e * 4);
    ushort* xh     = (ushort*)alloc((size_t)n * IN_DIM * 2);
    ushort* h1     = (ushort*)alloc((size_t)n * HID * 2);
    ushort* A1p    = (ushort*)alloc((size_t)Mp * IN_DIM * 2);
    ushort* A2p    = (ushort*)alloc((size_t)Mp * HID * 2);
    ushort* B1p    = (ushort*)alloc((size_t)IN_DIM * 256 * 2);
    ushort* B2p    = (ushort*)alloc((size_t)HID * 256 * 2);

    int nb = (n + 255) / 256;   // 196 (<= 256 required by scan_rest)
    int eb = (e + 255) / 256;

    zero_int2<<<nb, 256, 0, stream>>>(deg, cursor, n);
    count_deg<<<eb, 256, 0, stream>>>(dst, deg, e);

    scan_partial<<<nb, 256, 0, stream>>>(deg, escan, bsum, dinv, n);
    scan_rest<<<nb, 256, 0, stream>>>(escan, bsum, nb, rowptr, n);

    scatter_edges<<<eb, 256, 0, stream>>>(src, dst, rowptr, cursor, dinv, ssrc, ewt, e);

    int total4 = n * IN_DIM / 4;
    int cblocks = (IN_DIM * 64 + HID * 64 + total4 + 255) / 256;
    convert_inputs<<<cblocks, 256, 0, stream>>>(W1, B1p, W2, B2p, x, xh, total4);

    // layer 1: aggregate fp16 x -> A1 panel, fp16-MFMA GEMM -> fp16 h1
    aggregate_p<IN_DIM><<<(n + 3) / 4, 256, 0, stream>>>(xh, rowptr, ssrc, ewt, dinv,
                                                         A1p, n, Mp);
    gemm_f16<IN_DIM, 1><<<gblocks, 256, 0, stream>>>(A1p, B1p, b1, h1,
                                                     nullptr, nullptr, nullptr, n, Mp);

    // layer 2: aggregate fp16 h1 -> A2 panel, fp16-MFMA GEMM + final projection
    aggregate_p<HID><<<(n + 3) / 4, 256, 0, stream>>>(h1, rowptr, ssrc, ewt, dinv,
                                                      A2p, n, Mp);
    gemm_f16<HID, 2><<<gblocks, 256, 0, stream>>>(A2p, B2p, b2, nullptr,
                                                  Wl, bl, out, n, Mp);
}

// Round 12
// 256.777 us; speedup vs baseline: 1.8682x; 1.1008x over previous
//
#include <hip/hip_runtime.h>
#include <hip/hip_bf16.h>
#include <hip/hip_fp16.h>

constexpr int IN_DIM = 128;
constexpr int HID    = 256;

typedef _Float16 f16x8 __attribute__((ext_vector_type(8)));
typedef float    f32x4 __attribute__((ext_vector_type(4)));

// ---------------- setup kernels ----------------

__global__ void zero_int2(int* __restrict__ a, int* __restrict__ b, int n) {
    int i = blockIdx.x * blockDim.x + threadIdx.x;
    if (i < n) { a[i] = 0; b[i] = 0; }
}

__global__ void count_deg(const int* __restrict__ dst, int* __restrict__ deg, int e) {
    int i = blockIdx.x * blockDim.x + threadIdx.x;
    if (i < e) atomicAdd(&deg[dst[i]], 1);
}

// ---- scan phase 1: per-block scan + block total; also emits dinv ----
__global__ __launch_bounds__(256) void scan_partial(const int* __restrict__ deg,
                                                    int* __restrict__ escan,
                                                    int* __restrict__ blocksum,
                                                    float* __restrict__ dinv, int n) {
    __shared__ int lds[256];
    int t = threadIdx.x;
    int i = blockIdx.x * 256 + t;
    int v = (i < n) ? deg[i] : 0;
    if (i < n) dinv[i] = rsqrtf((float)v + 1.0f);
    lds[t] = v;
    __syncthreads();
    for (int off = 1; off < 256; off <<= 1) {
        int a = lds[t];
        int w = (t >= off) ? lds[t - off] : 0;
        __syncthreads();
        lds[t] = a + w;
        __syncthreads();
    }
    if (i < n) escan[i] = lds[t] - v;
    if (t == 255) blocksum[blockIdx.x] = lds[255];
}

// ---- scan phases 2+3 fused ----
__global__ __launch_bounds__(256) void scan_rest(const int* __restrict__ escan,
                                                 const int* __restrict__ blocksum,
                                                 int nb, int* __restrict__ rowptr, int n) {
    __shared__ int lds[256];
    int t = threadIdx.x;
    int v = (t < nb) ? blocksum[t] : 0;
    lds[t] = v;
    __syncthreads();
    for (int off = 1; off < 256; off <<= 1) {
        int a = lds[t];
        int w = (t >= off) ? lds[t - off] : 0;
        __syncthreads();
        lds[t] = a + w;
        __syncthreads();
    }
    int boff = (blockIdx.x > 0) ? lds[blockIdx.x - 1] : 0;
    int i = blockIdx.x * 256 + t;
    if (i < n) rowptr[i] = escan[i] + boff;
    if (blockIdx.x == 0 && t == 0) rowptr[n] = lds[nb - 1];
}

__global__ void scatter_edges(const int* __restrict__ src, const int* __restrict__ dst,
                              const int* __restrict__ rowptr, int* __restrict__ cursor,
                              const float* __restrict__ dinv,
                              int* __restrict__ ssrc, float* __restrict__ ewt, int e) {
    int i = blockIdx.x * blockDim.x + threadIdx.x;
    if (i < e) {
        int d = dst[i];
        int s = src[i];
        int p = atomicAdd(&cursor[d], 1);
        int idx = rowptr[d] + p;
        ssrc[idx] = s;
        ewt[idx]  = dinv[s] * dinv[d];
    }
}

// ---- fused input conversion: W1 -> B1 panel, W2 -> B2 panel, x -> fp16 ----
__device__ inline void conv_B_elem(const float* B, ushort* Bp, int id, int /*K*/) {
    int k  = id >> 6;
    int n4 = (id & 63) * 4;
    float4 v = *(const float4*)(B + (size_t)k * 256 + n4);
    size_t base = (size_t)(k >> 5) * (256 * 32) + (k & 31);
    Bp[base + (size_t)(n4 + 0) * 32] = __half_as_ushort(__float2half(v.x));
    Bp[base + (size_t)(n4 + 1) * 32] = __half_as_ushort(__float2half(v.y));
    Bp[base + (size_t)(n4 + 2) * 32] = __half_as_ushort(__float2half(v.z));
    Bp[base + (size_t)(n4 + 3) * 32] = __half_as_ushort(__float2half(v.w));
}

__global__ void convert_inputs(const float* __restrict__ W1, ushort* __restrict__ B1p,
                               const float* __restrict__ W2, ushort* __restrict__ B2p,
                               const float* __restrict__ x, ushort* __restrict__ xh,
                               int total4) {
    int id = blockIdx.x * 256 + threadIdx.x;
    if (id < IN_DIM * 64) {
        conv_B_elem(W1, B1p, id, IN_DIM);
    } else if (id < IN_DIM * 64 + HID * 64) {
        conv_B_elem(W2, B2p, id - IN_DIM * 64, HID);
    } else {
        int i = id - (IN_DIM * 64 + HID * 64);
        if (i < total4) {
            float4 v = *(const float4*)(x + (size_t)i * 4);
            ushort4 o;
            o.x = __half_as_ushort(__float2half(v.x));
            o.y = __half_as_ushort(__float2half(v.y));
            o.z = __half_as_ushort(__float2half(v.z));
            o.w = __half_as_ushort(__float2half(v.w));
            *(ushort4*)(xh + (size_t)i * 4) = o;
        }
    }
}

// ---------------- aggregation: one wave per node, fp16 gather, 8-deep MLP --
// fp32 accum; writes result as fp16 panel in MFMA layout [k>>5][row][k&31],
// chunk stride Mp*32. Inner loop batches 8 independent row loads before any
// use so each wave keeps 8 gathers in flight (latency-bound fix, R11).
template <int K>  // K halves per row: 128 or 256
__global__ __launch_bounds__(256) void aggregate_p(const ushort* __restrict__ h,
                                                   const int* __restrict__ rowptr,
                                                   const int* __restrict__ ssrc,
                                                   const float* __restrict__ ewt,
                                                   const float* __restrict__ dinv,
                                                   ushort* __restrict__ Pp,
                                                   int n, int Mp) {
    constexpr int VH = K / 64;  // halves per lane: 2 or 4
    int wid  = (blockIdx.x * 256 + threadIdx.x) >> 6;
    int lane = threadIdx.x & 63;
    if (wid >= n) return;
    float di = dinv[wid];
    float sw = di * di;
    float acc[VH];
    {
        const ushort* row = h + (size_t)wid * K + lane * VH;
        if constexpr (VH == 4) {
            uint2 u = *(const uint2*)row;
            float2 fa = __half22float2(*(__half2*)&u.x);
            float2 fb = __half22float2(*(__half2*)&u.y);
            acc[0] = fa.x * sw; acc[1] = fa.y * sw; acc[2] = fb.x * sw; acc[3] = fb.y * sw;
        } else {
            uint u = *(const uint*)row;
            float2 fa = __half22float2(*(__half2*)&u);
            acc[0] = fa.x * sw; acc[1] = fa.y * sw;
        }
    }
    int beg = rowptr[wid], fin = rowptr[wid + 1];
    for (int b = beg; b < fin; b += 64) {
        int cnt = fin - b;
        if (cnt > 64) cnt = 64;
        int   sv = (lane < cnt) ? ssrc[b + lane] : 0;
        float wv = (lane < cnt) ? ewt[b + lane]  : 0.f;
        int t = 0;
        // 8-wide: all loads issued before any use -> 8 outstanding per wave
        for (; t + 8 <= cnt; t += 8) {
            float wr[8];
            if constexpr (VH == 4) {
                uint2 u[8];
#pragma unroll
                for (int k = 0; k < 8; k++) {
                    int s = __shfl(sv, t + k);
                    wr[k] = __shfl(wv, t + k);
                    u[k] = *(const uint2*)(h + (size_t)s * K + lane * VH);
                }
#pragma unroll
                for (int k = 0; k < 8; k++) {
                    float2 fa = __half22float2(*(__half2*)&u[k].x);
                    float2 fb = __half22float2(*(__half2*)&u[k].y);
                    acc[0] += fa.x * wr[k]; acc[1] += fa.y * wr[k];
                    acc[2] += fb.x * wr[k]; acc[3] += fb.y * wr[k];
                }
            } else {
                uint u[8];
#pragma unroll
                for (int k = 0; k < 8; k++) {
                    int s = __shfl(sv, t + k);
                    wr[k] = __shfl(wv, t + k);
                    u[k] = *(const uint*)(h + (size_t)s * K + lane * VH);
                }
#pragma unroll
                for (int k = 0; k < 8; k++) {
                    float2 fa = __half22float2(*(__half2*)&u[k]);
                    acc[0] += fa.x * wr[k]; acc[1] += fa.y * wr[k];
                }
            }
        }
        // 4-wide tail
        for (; t + 4 <= cnt; t += 4) {
            float wr[4];
            if constexpr (VH == 4) {
                uint2 u[4];
#pragma unroll
                for (int k = 0; k < 4; k++) {
                    int s = __shfl(sv, t + k);
                    wr[k] = __shfl(wv, t + k);
                    u[k] = *(const uint2*)(h + (size_t)s * K + lane * VH);
                }
#pragma unroll
                for (int k = 0; k < 4; k++) {
                    float2 fa = __half22float2(*(__half2*)&u[k].x);
                    float2 fb = __half22float2(*(__half2*)&u[k].y);
                    acc[0] += fa.x * wr[k]; acc[1] += fa.y * wr[k];
                    acc[2] += fb.x * wr[k]; acc[3] += fb.y * wr[k];
                }
            } else {
                uint u[4];
#pragma unroll
                for (int k = 0; k < 4; k++) {
                    int s = __shfl(sv, t + k);
                    wr[k] = __shfl(wv, t + k);
                    u[k] = *(const uint*)(h + (size_t)s * K + lane * VH);
                }
#pragma unroll
                for (int k = 0; k < 4; k++) {
                    float2 fa = __half22float2(*(__half2*)&u[k]);
                    acc[0] += fa.x * wr[k]; acc[1] += fa.y * wr[k];
                }
            }
        }
        // scalar tail
        for (; t < cnt; t++) {
            int   s = __shfl(sv, t);
            float w = __shfl(wv, t);
            const ushort* r = h + (size_t)s * K + lane * VH;
            if constexpr (VH == 4) {
                uint2 u = *(const uint2*)r;
                float2 fa = __half22float2(*(__half2*)&u.x);
                float2 fb = __half22float2(*(__half2*)&u.y);
                acc[0] += fa.x * w; acc[1] += fa.y * w;
                acc[2] += fb.x * w; acc[3] += fb.y * w;
            } else {
                uint u = *(const uint*)r;
                float2 fa = __half22float2(*(__half2*)&u);
                acc[0] += fa.x * w; acc[1] += fa.y * w;
            }
        }
    }
    int kglob = lane * VH;
    int chunk = kglob >> 5;
    int inner = kglob & 31;
    size_t base = (size_t)chunk * Mp * 32 + (size_t)wid * 32 + inner;
    if constexpr (VH == 4) {
        __half2 p0 = __floats2half2_rn(acc[0], acc[1]);
        __half2 p1 = __floats2half2_rn(acc[2], acc[3]);
        *(uint2*)&Pp[base] = make_uint2(*(uint*)&p0, *(uint*)&p1);
    } else {
        __half2 p0 = __floats2half2_rn(acc[0], acc[1]);
        *(uint*)&Pp[base] = *(uint*)&p0;
    }
}

// ---------------- fp16 MFMA GEMM, BM=32 ------------------------------------
// A panel [K/32][Mp][32] fp16: block DMAs its 32-row A tile to LDS up front,
// one barrier, then barrier-free K-loop (A via ds_read_b128, B from L2,
// double-buffered).
// MODE 1: C16[M,256] = fp16(relu(A@B + bias))
// MODE 2: out[M,2]  = relu(A@B + bias) @ Wl + bl
template <int K, int MODE>
__global__ __launch_bounds__(256, 4) void gemm_f16(const ushort* __restrict__ Ap,
                                                   const ushort* __restrict__ Bp,
                                                   const float* __restrict__ bias,
                                                   ushort* __restrict__ C16,
                                                   const float* __restrict__ Wl,
                                                   const float* __restrict__ bl,
                                                   float* __restrict__ out,
                                                   int M, int Mp) {
    constexpr int NC = K / 32;
    __shared__ ushort Asm[NC * 1024];
    __shared__ float part[4][32][2];

    int tid  = threadIdx.x;
    int w    = tid >> 6;
    int lane = tid & 63;
    int l15  = lane & 15;
    int quad = lane >> 4;
    int row0 = blockIdx.x * 32;

    constexpr int TOT = NC * 2;
    for (int j = w; j < TOT; j += 4) {
        int c   = j >> 1;
        int sub = j & 1;
        const ushort* g = Ap + (size_t)c * Mp * 32 + (size_t)(row0 + sub * 16) * 32;
        ushort* l = Asm + c * 1024 + sub * 512;
        __builtin_amdgcn_global_load_lds(
            (const __attribute__((address_space(1))) uint*)(g + (size_t)lane * 8),
            (__attribute__((address_space(3))) uint*)l, 16, 0, 0);
    }
    __syncthreads();

    size_t bco[4];
#pragma unroll
    for (int j = 0; j < 4; j++) bco[j] = (size_t)(w * 64 + j * 16 + l15) * 32 + quad * 8;

    f16x8 fb[2][4];
    auto loadB = [&](int c, int buf) {
        const ushort* bp = Bp + (size_t)c * 256 * 32;
#pragma unroll
        for (int j = 0; j < 4; j++) fb[buf][j] = *(const f16x8*)(bp + bco[j]);
    };

    f32x4 acc[2][4] = {};
    loadB(0, 0);
#pragma unroll
    for (int c = 0; c < NC; c++) {
        int cur = c & 1;
        if (c + 1 < NC) loadB(c + 1, cur ^ 1);
        f16x8 fa[2];
#pragma unroll
        for (int i = 0; i < 2; i++) {
            int off = c * 1024 + (i * 16 + l15) * 32 + quad * 8;
            fa[i] = *(const f16x8*)&Asm[off];
        }
#pragma unroll
        for (int i = 0; i < 2; i++)
#pragma unroll
            for (int j = 0; j < 4; j++)
                acc[i][j] = __builtin_amdgcn_mfma_f32_16x16x32_f16(fa[i], fb[cur][j], acc[i][j], 0, 0, 0);
    }

    float bj[4];
#pragma unroll
    for (int j = 0; j < 4; j++) bj[j] = bias[w * 64 + j * 16 + l15];

    if constexpr (MODE == 1) {
#pragma unroll
        for (int i = 0; i < 2; i++)
#pragma unroll
            for (int reg = 0; reg < 4; reg++) {
                int r = row0 + i * 16 + quad * 4 + reg;
                if (r < M) {
                    ushort* cp = C16 + (size_t)r * 256 + w * 64 + l15;
#pragma unroll
                    for (int j = 0; j < 4; j++) {
                        float v = fmaxf(acc[i][j][reg] + bj[j], 0.f);
                        cp[j * 16] = __half_as_ushort(__float2half(v));
                    }
                }
            }
    } else {
        float wl0[4], wl1[4];
#pragma unroll
        for (int j = 0; j < 4; j++) {
            int cj = w * 64 + j * 16 + l15;
            float2 wv = *(const float2*)(Wl + cj * 2);
            wl0[j] = wv.x; wl1[j] = wv.y;
        }
#pragma unroll
        for (int i = 0; i < 2; i++)
#pragma unroll
            for (int reg = 0; reg < 4; reg++) {
                float s0 = 0.f, s1 = 0.f;
#pragma unroll
                for (int j = 0; j < 4; j++) {
                    float v = fmaxf(acc[i][j][reg] + bj[j], 0.f);
                    s0 += v * wl0[j];
                    s1 += v * wl1[j];
                }
#pragma unroll
                for (int off = 1; off < 16; off <<= 1) {
                    s0 += __shfl_xor(s0, off);
                    s1 += __shfl_xor(s1, off);
                }
                if (l15 == 0) {
                    int r = i * 16 + quad * 4 + reg;
                    part[w][r][0] = s0;
                    part[w][r][1] = s1;
                }
            }
        __syncthreads();
        if (tid < 64) {
            int r = tid >> 1, o = tid & 1;
            int grr = row0 + r;
            if (grr < M) {
                float s = part[0][r][o] + part[1][r][o] + part[2][r][o] + part[3][r][o] + bl[o];
                out[(size_t)grr * 2 + o] = s;
            }
        }
    }
}

// ---------------- launch ----------------

extern "C" void kernel_launch(void* const* d_in, const int* in_sizes, int n_in,
                              void* d_out, int out_size, void* d_ws, size_t ws_size,
                              hipStream_t stream) {
    const float* x  = (const float*)d_in[0];
    const int*   ei = (const int*)d_in[1];
    const float* W1 = (const float*)d_in[2];
    const float* b1 = (const float*)d_in[3];
    const float* W2 = (const float*)d_in[4];
    const float* b2 = (const float*)d_in[5];
    const float* Wl = (const float*)d_in[6];
    const float* bl = (const float*)d_in[7];
    float* out = (float*)d_out;

    int n = in_sizes[0] / IN_DIM;  // 50000
    int e = in_sizes[1] / 2;       // 600000
    const int* src = ei;
    const int* dst = ei + e;

    int gblocks = (n + 31) / 32;   // BM=32
    int Mp = gblocks * 32;

    char* ws = (char*)d_ws;
    size_t off = 0;
    auto alloc = [&](size_t bytes) -> void* {
        void* p = ws + off;
        off += (bytes + 255) & ~(size_t)255;
        return p;
    };
    int*    deg    = (int*)alloc((size_t)n * 4);
    int*    cursor = (int*)alloc((size_t)n * 4);
    float*  dinv   = (float*)alloc((size_t)n * 4);
    int*    rowptr = (int*)alloc((size_t)(n + 1) * 4);
    int*    escan  = (int*)alloc((size_t)n * 4);
    int*    bsum   = (int*)alloc(256 * 4);
    int*    ssrc   = (int*)alloc((size_t)e * 4);
    float*  ewt    = (float*)alloc((size_t)e * 4);
    ushort* xh     = (ushort*)alloc((size_t)n * IN_DIM * 2);
    ushort* h1     = (ushort*)alloc((size_t)n * HID * 2);
    ushort* A1p    = (ushort*)alloc((size_t)Mp * IN_DIM * 2);
    ushort* A2p    = (ushort*)alloc((size_t)Mp * HID * 2);
    ushort* B1p    = (ushort*)alloc((size_t)IN_DIM * 256 * 2);
    ushort* B2p    = (ushort*)alloc((size_t)HID * 256 * 2);

    int nb = (n + 255) / 256;   // 196 (<= 256 required by scan_rest)
    int eb = (e + 255) / 256;

    zero_int2<<<nb, 256, 0, stream>>>(deg, cursor, n);
    count_deg<<<eb, 256, 0, stream>>>(dst, deg, e);

    scan_partial<<<nb, 256, 0, stream>>>(deg, escan, bsum, dinv, n);
    scan_rest<<<nb, 256, 0, stream>>>(escan, bsum, nb, rowptr, n);

    scatter_edges<<<eb, 256, 0, stream>>>(src, dst, rowptr, cursor, dinv, ssrc, ewt, e);

    int total4 = n * IN_DIM / 4;
    int cblocks = (IN_DIM * 64 + HID * 64 + total4 + 255) / 256;
    convert_inputs<<<cblocks, 256, 0, stream>>>(W1, B1p, W2, B2p, x, xh, total4);

    // layer 1: aggregate fp16 x -> A1 panel, fp16-MFMA GEMM -> fp16 h1
    aggregate_p<IN_DIM><<<(n + 3) / 4, 256, 0, stream>>>(xh, rowptr, ssrc, ewt, dinv,
                                                         A1p, n, Mp);
    gemm_f16<IN_DIM, 1><<<gblocks, 256, 0, stream>>>(A1p, B1p, b1, h1,
                                                     nullptr, nullptr, nullptr, n, Mp);

    // layer 2: aggregate fp16 h1 -> A2 panel, fp16-MFMA GEMM + final projection
    aggregate_p<HID><<<(n + 3) / 4, 256, 0, stream>>>(h1, rowptr, ssrc, ewt, dinv,
                                                      A2p, n, Mp);
    gemm_f16<HID, 2><<<gblocks, 256, 0, stream>>>(A2p, B2p, b2, nullptr,
                                                  Wl, bl, out, n, Mp);
}